// Round 9
// baseline (471.383 us; speedup 1.0000x reference)
//
#include <hip/hip_runtime.h>
#include <cstddef>

#define EPS 1e-5f

typedef __attribute__((ext_vector_type(8))) short bf16x8;
typedef __attribute__((ext_vector_type(8))) unsigned short u16x8;
typedef __attribute__((ext_vector_type(4))) float f32x4;

__device__ inline short f2bf(float f) {
    union { float f; unsigned u; } v;
    v.f = f;
    unsigned r = v.u + 0x7fff + ((v.u >> 16) & 1);  // RNE
    return (short)(r >> 16);
}
__device__ inline float bf2f(unsigned short s) {
    union { unsigned u; float f; } v;
    v.u = ((unsigned)s) << 16;
    return v.f;
}

// ================= CSR build (by dst) =================
__global__ void hist_kernel(const int* __restrict__ dst, int E, int* __restrict__ counts) {
    int i = blockIdx.x * blockDim.x + threadIdx.x;
    if (i < E) atomicAdd(&counts[dst[i]], 1);
}

__global__ __launch_bounds__(1024) void scan_part(const int* __restrict__ counts,
                                                  int* __restrict__ rowptr,
                                                  int* __restrict__ aux, int n) {
    __shared__ int sh[1024];
    int t = threadIdx.x;
    int g = blockIdx.x * 1024 + t;
    int v = (g < n) ? counts[g] : 0;
    sh[t] = v;
    __syncthreads();
    for (int off = 1; off < 1024; off <<= 1) {
        int add = (t >= off) ? sh[t - off] : 0;
        __syncthreads();
        sh[t] += add;
        __syncthreads();
    }
    if (g < n) rowptr[g] = sh[t] - v;
    if (t == 1023) aux[blockIdx.x] = sh[t];
}

__global__ __launch_bounds__(128) void scan_aux(int* __restrict__ aux, int B) {
    __shared__ int sh[128];
    int t = threadIdx.x;
    int v = (t < B) ? aux[t] : 0;
    sh[t] = v;
    __syncthreads();
    for (int off = 1; off < 128; off <<= 1) {
        int add = (t >= off) ? sh[t - off] : 0;
        __syncthreads();
        sh[t] += add;
        __syncthreads();
    }
    if (t < B) aux[t] = sh[t] - v;
}

// finishes rowptr, seeds fill cursor, computes dinv (all fused)
__global__ void scan_add(int* __restrict__ rowptr, const int* __restrict__ aux,
                         const int* __restrict__ counts, int* __restrict__ cur,
                         float* __restrict__ dinv, int n, int E) {
    int g = blockIdx.x * blockDim.x + threadIdx.x;
    if (g < n) {
        int r = rowptr[g] + aux[g >> 10];
        rowptr[g] = r;
        cur[g] = r;
        dinv[g] = rsqrtf((float)counts[g] + 1.0f);
    }
    if (g == 0) rowptr[n] = E;
}

__global__ void fill_kernel(const int* __restrict__ src, const int* __restrict__ dst, int E,
                            int* __restrict__ cur, const float* __restrict__ dinv,
                            int* __restrict__ esrc, float* __restrict__ ewt) {
    int e = blockIdx.x * blockDim.x + threadIdx.x;
    if (e < E) {
        int d = dst[e];
        int s = src[e];
        int p = atomicAdd(&cur[d], 1);
        esrc[p] = s;
        ewt[p] = dinv[s] * dinv[d];
    }
}

// ================= both weight transposes + bf16 in one launch =================
__global__ void wt_all_kernel(const float* __restrict__ W1, const float* __restrict__ W2,
                              unsigned short* __restrict__ Wt1, unsigned short* __restrict__ Wt2) {
    int o = blockIdx.x * blockDim.x + threadIdx.x;
    if (o < 32 * 128) {
        int c = o / 32, k = o % 32;  // Wt1[c][k]
        Wt1[o] = (unsigned short)f2bf(W1[(size_t)k * 128 + c]);
    } else if (o < 32 * 128 + 128 * 128) {
        int o2 = o - 32 * 128;
        int c = o2 / 128, k = o2 % 128;
        Wt2[o2] = (unsigned short)f2bf(W2[(size_t)k * 128 + c]);
    }
}

// ================= MFMA GEMM: out[n,128] = norm(hb[n,K]) @ W, bf16 in/out =================
// STATS barrier is fine here: uniform work per block.
template <int K, bool NORM, bool STATS>
__global__ __launch_bounds__(256) void gemm_mfma(const unsigned short* __restrict__ hb,
                                                 const unsigned short* __restrict__ Wt,
                                                 const float* __restrict__ ss,
                                                 unsigned short* __restrict__ outb,
                                                 float* __restrict__ sums, int n) {
    int wid = (blockIdx.x * 256 + threadIdx.x) >> 6;
    int wv = (threadIdx.x >> 6);
    int lane = threadIdx.x & 63;
    int m = lane & 15;
    int qd = lane >> 4;
    int r0 = wid * 32;
    if (!STATS && r0 >= n) return;

    f32x4 acc[2][8];
#pragma unroll
    for (int rt = 0; rt < 2; rt++)
#pragma unroll
        for (int ct = 0; ct < 8; ct++) acc[rt][ct] = (f32x4){0.f, 0.f, 0.f, 0.f};

    if (r0 < n) {
#pragma unroll
        for (int q = 0; q < K / 32; q++) {
            int k0 = q * 32 + qd * 8;
            bf16x8 a[2];
#pragma unroll
            for (int rt = 0; rt < 2; rt++) {
                int r = r0 + rt * 16 + m;
                bf16x8 av = (bf16x8){0, 0, 0, 0, 0, 0, 0, 0};
                if (r < n) av = *(const bf16x8*)(hb + (size_t)r * K + k0);
                if (NORM) {
#pragma unroll
                    for (int j = 0; j < 8; j++) {
                        float f = bf2f((unsigned short)av[j]);
                        f = fmaxf(fmaf(f, ss[k0 + j], ss[K + k0 + j]), 0.f);
                        av[j] = f2bf(f);
                    }
                }
                a[rt] = av;
            }
#pragma unroll
            for (int ct = 0; ct < 8; ct++) {
                bf16x8 b = *(const bf16x8*)(Wt + (size_t)(ct * 16 + m) * K + k0);
                acc[0][ct] = __builtin_amdgcn_mfma_f32_16x16x32_bf16(a[0], b, acc[0][ct], 0, 0, 0);
                acc[1][ct] = __builtin_amdgcn_mfma_f32_16x16x32_bf16(a[1], b, acc[1][ct], 0, 0, 0);
            }
        }
#pragma unroll
        for (int rt = 0; rt < 2; rt++)
#pragma unroll
            for (int i = 0; i < 4; i++) {
                int r = r0 + rt * 16 + qd * 4 + i;
                if (r < n) {
#pragma unroll
                    for (int ct = 0; ct < 8; ct++)
                        outb[(size_t)r * 128 + ct * 16 + m] = (unsigned short)f2bf(acc[rt][ct][i]);
                }
            }
    }

    if (STATS) {
        __shared__ float ls[4][128], lq[4][128];
#pragma unroll
        for (int ct = 0; ct < 8; ct++) {
            float s = 0.f, q = 0.f;
#pragma unroll
            for (int rt = 0; rt < 2; rt++)
#pragma unroll
                for (int i = 0; i < 4; i++) {
                    float v = acc[rt][ct][i];
                    s += v;
                    q += v * v;
                }
            s += __shfl_xor(s, 16, 64);
            s += __shfl_xor(s, 32, 64);
            q += __shfl_xor(q, 16, 64);
            q += __shfl_xor(q, 32, 64);
            if (qd == 0) {
                ls[wv][ct * 16 + m] = s;
                lq[wv][ct * 16 + m] = q;
            }
        }
        __syncthreads();
        int t = threadIdx.x;
        if (t < 128) {
            atomicAdd(&sums[t], ls[0][t] + ls[1][t] + ls[2][t] + ls[3][t]);
        } else {
            int c = t - 128;
            atomicAdd(&sums[128 + c], lq[0][c] + lq[1][c] + lq[2][c] + lq[3][c]);
        }
    }
}

// GEMV, bf16 input, fused norm: out[n] = relu(hb[n,128]*S+T) @ W[128]
__global__ void gemv_norm_bf(const unsigned short* __restrict__ hb, const float* __restrict__ W,
                             const float* __restrict__ ss, float* __restrict__ out, int n) {
    int gid = blockIdx.x * blockDim.x + threadIdx.x;
    int wid = gid >> 6, lane = gid & 63;
    int nw = (gridDim.x * blockDim.x) >> 6;
    int c = lane * 2;
    float w0 = W[c], w1 = W[c + 1];
    float s0 = ss[c], s1 = ss[c + 1];
    float t0 = ss[128 + c], t1 = ss[128 + c + 1];
    for (int r = wid; r < n; r += nw) {
        ushort2 u = ((const ushort2*)(hb + (size_t)r * 128))[lane];
        float a = fmaxf(fmaf(bf2f(u.x), s0, t0), 0.f);
        float b = fmaxf(fmaf(bf2f(u.y), s1, t1), 0.f);
        float v = fmaf(a, w0, b * w1);
#pragma unroll
        for (int off = 32; off > 0; off >>= 1) v += __shfl_down(v, off, 64);
        if (lane == 0) out[r] = v;
    }
}

// ================= agg128: 8 nodes/block, 32 lanes/node, no barrier ==========
__global__ __launch_bounds__(256) void agg128_bf(const unsigned short* __restrict__ tmp,
                                                 const int* __restrict__ rowptr,
                                                 const int* __restrict__ esrc,
                                                 const float* __restrict__ ewt,
                                                 const float* __restrict__ dinv,
                                                 unsigned short* __restrict__ agg, int n) {
    int node = (blockIdx.x << 3) + (threadIdx.x >> 5);
    if (node >= n) return;
    int c4 = threadIdx.x & 31;  // ushort4 channel group
    float di = dinv[node];
    float d2 = di * di;
    ushort4 t = ((const ushort4*)tmp)[(size_t)node * 32 + c4];
    float a0 = bf2f(t.x) * d2, a1 = bf2f(t.y) * d2, a2 = bf2f(t.z) * d2, a3 = bf2f(t.w) * d2;
    int j = rowptr[node], je = rowptr[node + 1];
    for (; j + 8 <= je; j += 8) {
        int s[8];
        float w[8];
        ushort4 v[8];
#pragma unroll
        for (int k = 0; k < 8; k++) { s[k] = esrc[j + k]; w[k] = ewt[j + k]; }
#pragma unroll
        for (int k = 0; k < 8; k++) v[k] = ((const ushort4*)tmp)[(size_t)s[k] * 32 + c4];
#pragma unroll
        for (int k = 0; k < 8; k++) {
            a0 = fmaf(bf2f(v[k].x), w[k], a0);
            a1 = fmaf(bf2f(v[k].y), w[k], a1);
            a2 = fmaf(bf2f(v[k].z), w[k], a2);
            a3 = fmaf(bf2f(v[k].w), w[k], a3);
        }
    }
    if (j + 4 <= je) {
        int s[4];
        float w[4];
        ushort4 v[4];
#pragma unroll
        for (int k = 0; k < 4; k++) { s[k] = esrc[j + k]; w[k] = ewt[j + k]; }
#pragma unroll
        for (int k = 0; k < 4; k++) v[k] = ((const ushort4*)tmp)[(size_t)s[k] * 32 + c4];
#pragma unroll
        for (int k = 0; k < 4; k++) {
            a0 = fmaf(bf2f(v[k].x), w[k], a0);
            a1 = fmaf(bf2f(v[k].y), w[k], a1);
            a2 = fmaf(bf2f(v[k].z), w[k], a2);
            a3 = fmaf(bf2f(v[k].w), w[k], a3);
        }
        j += 4;
    }
    for (; j < je; j++) {
        int s = esrc[j];
        float w = ewt[j];
        ushort4 v = ((const ushort4*)tmp)[(size_t)s * 32 + c4];
        a0 = fmaf(bf2f(v.x), w, a0);
        a1 = fmaf(bf2f(v.y), w, a1);
        a2 = fmaf(bf2f(v.z), w, a2);
        a3 = fmaf(bf2f(v.w), w, a3);
    }
    ushort4 o;
    o.x = (unsigned short)f2bf(a0);
    o.y = (unsigned short)f2bf(a1);
    o.z = (unsigned short)f2bf(a2);
    o.w = (unsigned short)f2bf(a3);
    ((ushort4*)agg)[(size_t)node * 32 + c4] = o;
}

// ================= stats over bf16 matrix (separate streaming kernel, uniform work) =====
__global__ __launch_bounds__(256) void stats128_bf(const unsigned short* __restrict__ a,
                                                   float* __restrict__ sums, int n) {
    __shared__ float ls[16][128], lq[16][128];
    int t = threadIdx.x;
    int rg = t >> 4;        // row group 0..15
    int cg = t & 15;        // channel group: channels cg*8..cg*8+7
    float s[8], q[8];
#pragma unroll
    for (int k = 0; k < 8; k++) { s[k] = 0.f; q[k] = 0.f; }
    for (int r = blockIdx.x * 16 + rg; r < n; r += gridDim.x * 16) {
        u16x8 v = *(const u16x8*)(a + (size_t)r * 128 + cg * 8);
#pragma unroll
        for (int k = 0; k < 8; k++) {
            float f = bf2f(v[k]);
            s[k] += f;
            q[k] = fmaf(f, f, q[k]);
        }
    }
#pragma unroll
    for (int k = 0; k < 8; k++) {
        ls[rg][cg * 8 + k] = s[k];
        lq[rg][cg * 8 + k] = q[k];
    }
    __syncthreads();
    if (t < 128) {
        float v = 0.f;
#pragma unroll
        for (int i = 0; i < 16; i++) v += ls[i][t];
        atomicAdd(&sums[t], v);
    } else {
        int c = t - 128;
        float v = 0.f;
#pragma unroll
        for (int i = 0; i < 16; i++) v += lq[i][c];
        atomicAdd(&sums[128 + c], v);
    }
}

// ================= agg32: gather fp32 x directly, 8 lanes/node, float4 loads ============
__global__ __launch_bounds__(256) void agg32_f(const float* __restrict__ x,
                                               const int* __restrict__ rowptr,
                                               const int* __restrict__ esrc,
                                               const float* __restrict__ ewt,
                                               const float* __restrict__ dinv,
                                               unsigned short* __restrict__ xab, int n) {
    int g = threadIdx.x >> 3;   // 32 groups of 8 lanes
    int lane = threadIdx.x & 7;
    int node = blockIdx.x * 32 + g;
    if (node >= n) return;
    int co = lane << 2;
    float di = dinv[node];
    float d2 = di * di;
    float4 a = *(const float4*)(x + ((size_t)node << 5) + co);
    a.x *= d2; a.y *= d2; a.z *= d2; a.w *= d2;
    int j = rowptr[node], je = rowptr[node + 1];
    for (; j + 4 <= je; j += 4) {
        int s0 = esrc[j], s1 = esrc[j + 1], s2 = esrc[j + 2], s3 = esrc[j + 3];
        float w0 = ewt[j], w1 = ewt[j + 1], w2 = ewt[j + 2], w3 = ewt[j + 3];
        float4 v0 = *(const float4*)(x + ((size_t)s0 << 5) + co);
        float4 v1 = *(const float4*)(x + ((size_t)s1 << 5) + co);
        float4 v2 = *(const float4*)(x + ((size_t)s2 << 5) + co);
        float4 v3 = *(const float4*)(x + ((size_t)s3 << 5) + co);
        a.x = fmaf(v0.x, w0, a.x); a.y = fmaf(v0.y, w0, a.y);
        a.z = fmaf(v0.z, w0, a.z); a.w = fmaf(v0.w, w0, a.w);
        a.x = fmaf(v1.x, w1, a.x); a.y = fmaf(v1.y, w1, a.y);
        a.z = fmaf(v1.z, w1, a.z); a.w = fmaf(v1.w, w1, a.w);
        a.x = fmaf(v2.x, w2, a.x); a.y = fmaf(v2.y, w2, a.y);
        a.z = fmaf(v2.z, w2, a.z); a.w = fmaf(v2.w, w2, a.w);
        a.x = fmaf(v3.x, w3, a.x); a.y = fmaf(v3.y, w3, a.y);
        a.z = fmaf(v3.z, w3, a.z); a.w = fmaf(v3.w, w3, a.w);
    }
    for (; j < je; j++) {
        int s = esrc[j];
        float w = ewt[j];
        float4 v = *(const float4*)(x + ((size_t)s << 5) + co);
        a.x = fmaf(v.x, w, a.x); a.y = fmaf(v.y, w, a.y);
        a.z = fmaf(v.z, w, a.z); a.w = fmaf(v.w, w, a.w);
    }
    ushort4 o;
    o.x = (unsigned short)f2bf(a.x);
    o.y = (unsigned short)f2bf(a.y);
    o.z = (unsigned short)f2bf(a.z);
    o.w = (unsigned short)f2bf(a.w);
    ((ushort4*)(xab + ((size_t)node << 5)))[lane] = o;
}

// ================= agg1 + fused wave-level stats — 4 sub-lanes per node =================
__global__ void agg1_stats(const float* __restrict__ tmp, const int* __restrict__ rowptr,
                           const int* __restrict__ esrc, const float* __restrict__ ewt,
                           const float* __restrict__ dinv, float* __restrict__ out,
                           float* __restrict__ sums, int n) {
    int gid = blockIdx.x * blockDim.x + threadIdx.x;
    int node = gid >> 2;
    int sl = gid & 3;
    float acc = 0.f;
    if (node < n) {
        int j = rowptr[node] + sl, je = rowptr[node + 1];
        for (; j < je; j += 4) acc = fmaf(tmp[esrc[j]], ewt[j], acc);
        // reduce over the 4 sub-lanes
        acc += __shfl_down(acc, 1, 4);
        acc += __shfl_down(acc, 2, 4);
        if (sl == 0) {
            float di = dinv[node];
            acc = fmaf(tmp[node], di * di, acc);
            out[node] = acc;
        } else {
            acc = 0.f;  // so stats counts each node once
        }
    }
    float s = acc, q = acc * acc;
#pragma unroll
    for (int off = 32; off > 0; off >>= 1) {
        s += __shfl_down(s, off, 64);
        q += __shfl_down(q, off, 64);
    }
    if ((threadIdx.x & 63) == 0) {
        atomicAdd(&sums[0], s);
        atomicAdd(&sums[1], q);
    }
}

// ================= finalize: fused BN->IN->LN (C=128) =================
template <int C>
__global__ void finalize_kernel(const float* __restrict__ sums, const float* __restrict__ g,
                                const float* __restrict__ lw, const float* __restrict__ lb,
                                float* __restrict__ ss, int n) {
    __shared__ float vt2[C];
    int c = threadIdx.x;
    float m = sums[c] / n;
    float v = sums[C + c] / n - m * m;
    v = v < 0.f ? 0.f : v;
    float gc = g[c];
    float bs = rsqrtf(v + EPS) * gc;
    float vz = v * bs * bs;
    float t = bs * rsqrtf(vz + EPS);
    vt2[c] = v * t * t;
    __syncthreads();
    if (c == 0) {
        float gv = 0.f;
        for (int i = 0; i < C; i++) gv += vt2[i];
        vt2[0] = gv / C;
    }
    __syncthreads();
    float GV = vt2[0];
    float S = t * rsqrtf(GV + EPS) * lw[c];
    ss[c] = S;
    ss[C + c] = lb[c] - m * S;
}

// apply with inline C=1 finalize
__global__ void apply1_kernel(const float* __restrict__ sums, const float* __restrict__ g,
                              const float* __restrict__ lw, const float* __restrict__ lb,
                              const float* __restrict__ a, float* __restrict__ out, int n) {
    int i = blockIdx.x * blockDim.x + threadIdx.x;
    if (i >= n) return;
    float m = sums[0] / n;
    float v = sums[1] / n - m * m;
    v = v < 0.f ? 0.f : v;
    float bs = rsqrtf(v + EPS) * g[0];
    float vz = v * bs * bs;
    float t = bs * rsqrtf(vz + EPS);
    float GV = v * t * t;
    float S = t * rsqrtf(GV + EPS) * lw[0];
    float T = lb[0] - m * S;
    out[i] = fmaf(a[i], S, T);
}

extern "C" void kernel_launch(void* const* d_in, const int* in_sizes, int n_in,
                              void* d_out, int out_size, void* d_ws, size_t ws_size,
                              hipStream_t stream) {
    const float* x = (const float*)d_in[0];
    const int* ei = (const int*)d_in[1];
    int n = in_sizes[0] / 32;
    int E = in_sizes[1] / 2;
    const int* src = ei;
    const int* dstp = ei + E;
    const float* W1 = (const float*)d_in[2];
    const float* g1 = (const float*)d_in[4];
    const float* lw1 = (const float*)d_in[6];
    const float* lb1 = (const float*)d_in[7];
    const float* W2 = (const float*)d_in[8];
    const float* g2 = (const float*)d_in[10];
    const float* lw2 = (const float*)d_in[12];
    const float* lb2 = (const float*)d_in[13];
    const float* W3 = (const float*)d_in[14];
    const float* g3 = (const float*)d_in[16];
    const float* lw3 = (const float*)d_in[18];
    const float* lb3 = (const float*)d_in[19];
    float* out = (float*)d_out;

    // workspace layout (16B-aligned chunks)
    char* p = (char*)d_ws;
    int* counts = (int*)p;             p += (size_t)n * 4;
    int* cur = (int*)p;                p += (size_t)n * 4;
    int* rowptr = (int*)p;             p += (size_t)(n + 4) * 4;
    int* aux = (int*)p;                p += 128 * 4;
    int* esrc = (int*)p;               p += (size_t)E * 4;
    float* ewt = (float*)p;            p += (size_t)E * 4;
    float* dinv = (float*)p;           p += (size_t)n * 4;
    unsigned short* Wt1 = (unsigned short*)p;  p += 128 * 32 * 2;
    unsigned short* Wt2 = (unsigned short*)p;  p += 128 * 128 * 2;
    unsigned short* xa = (unsigned short*)p;   p += (size_t)n * 32 * 2;
    unsigned short* h1 = (unsigned short*)p;   p += (size_t)n * 128 * 2;
    unsigned short* t2 = (unsigned short*)p;   p += (size_t)n * 128 * 2;
    unsigned short* a2 = (unsigned short*)p;   p += (size_t)n * 128 * 2;
    float* t3 = (float*)p;             p += (size_t)n * 4;
    float* a3 = (float*)p;             p += (size_t)n * 4;
    float* sums1 = (float*)p;          p += 256 * 4;
    float* sums2 = (float*)p;          p += 256 * 4;
    float* sums3 = (float*)p;          p += 4 * 4;
    float* ss1 = (float*)p;            p += 256 * 4;
    float* ss2 = (float*)p;            p += 256 * 4;

    int B = (n + 1023) / 1024;

    // ---- CSR build + prep ----
    hipMemsetAsync(counts, 0, (size_t)n * 4, stream);
    hipMemsetAsync(sums1, 0, 516 * 4, stream);
    hist_kernel<<<(E + 255) / 256, 256, 0, stream>>>(dstp, E, counts);
    scan_part<<<B, 1024, 0, stream>>>(counts, rowptr, aux, n);
    scan_aux<<<1, 128, 0, stream>>>(aux, B);
    scan_add<<<(n + 255) / 256, 256, 0, stream>>>(rowptr, aux, counts, cur, dinv, n, E);
    fill_kernel<<<(E + 255) / 256, 256, 0, stream>>>(src, dstp, E, cur, dinv, esrc, ewt);
    wt_all_kernel<<<(32 * 128 + 128 * 128 + 255) / 256, 256, 0, stream>>>(W1, W2, Wt1, Wt2);

    int mblk = ((n + 31) / 32 + 3) / 4;

    // ---- layer 1: agg(x) fp32->bf16 in 32-dim, MFMA GEMM 32->128 with fused stats ----
    agg32_f<<<(n + 31) / 32, 256, 0, stream>>>(x, rowptr, esrc, ewt, dinv, xa, n);
    gemm_mfma<32, false, true><<<mblk, 256, 0, stream>>>(xa, Wt1, nullptr, h1, sums1, n);
    finalize_kernel<128><<<1, 128, 0, stream>>>(sums1, g1, lw1, lb1, ss1, n);

    // ---- layer 2: MFMA GEMM 128->128 (norm fused), agg (no barrier), separate stats ----
    gemm_mfma<128, true, false><<<mblk, 256, 0, stream>>>(h1, Wt2, ss1, t2, nullptr, n);
    agg128_bf<<<(n + 7) / 8, 256, 0, stream>>>(t2, rowptr, esrc, ewt, dinv, a2, n);
    stats128_bf<<<512, 256, 0, stream>>>(a2, sums2, n);
    finalize_kernel<128><<<1, 128, 0, stream>>>(sums2, g2, lw2, lb2, ss2, n);

    // ---- layer 3: gemv (norm fused), agg+stats fused (4 lanes/node), apply ----
    gemv_norm_bf<<<1024, 256, 0, stream>>>(a2, W3, ss2, t3, n);
    agg1_stats<<<(n * 4 + 255) / 256, 256, 0, stream>>>(t3, rowptr, esrc, ewt, dinv, a3, sums3, n);
    apply1_kernel<<<(n + 255) / 256, 256, 0, stream>>>(sums3, g3, lw3, lb3, a3, out, n);
}

// Round 10
// 310.972 us; speedup vs baseline: 1.5158x; 1.5158x over previous
//
#include <hip/hip_runtime.h>
#include <cstddef>

#define EPS 1e-5f

typedef __attribute__((ext_vector_type(8))) short bf16x8;
typedef __attribute__((ext_vector_type(8))) unsigned short u16x8;
typedef __attribute__((ext_vector_type(4))) float f32x4;

__device__ inline short f2bf(float f) {
    union { float f; unsigned u; } v;
    v.f = f;
    unsigned r = v.u + 0x7fff + ((v.u >> 16) & 1);  // RNE
    return (short)(r >> 16);
}
__device__ inline float bf2f(unsigned short s) {
    union { unsigned u; float f; } v;
    v.u = ((unsigned)s) << 16;
    return v.f;
}

// ================= CSR build (by dst) =================
__global__ void hist_kernel(const int* __restrict__ dst, int E, int* __restrict__ counts) {
    int i = blockIdx.x * blockDim.x + threadIdx.x;
    if (i < E) atomicAdd(&counts[dst[i]], 1);
}

__global__ __launch_bounds__(1024) void scan_part(const int* __restrict__ counts,
                                                  int* __restrict__ rowptr,
                                                  int* __restrict__ aux, int n) {
    __shared__ int sh[1024];
    int t = threadIdx.x;
    int g = blockIdx.x * 1024 + t;
    int v = (g < n) ? counts[g] : 0;
    sh[t] = v;
    __syncthreads();
    for (int off = 1; off < 1024; off <<= 1) {
        int add = (t >= off) ? sh[t - off] : 0;
        __syncthreads();
        sh[t] += add;
        __syncthreads();
    }
    if (g < n) rowptr[g] = sh[t] - v;
    if (t == 1023) aux[blockIdx.x] = sh[t];
}

__global__ __launch_bounds__(128) void scan_aux(int* __restrict__ aux, int B) {
    __shared__ int sh[128];
    int t = threadIdx.x;
    int v = (t < B) ? aux[t] : 0;
    sh[t] = v;
    __syncthreads();
    for (int off = 1; off < 128; off <<= 1) {
        int add = (t >= off) ? sh[t - off] : 0;
        __syncthreads();
        sh[t] += add;
        __syncthreads();
    }
    if (t < B) aux[t] = sh[t] - v;
}

// finishes rowptr, seeds fill cursor, computes dinv (all fused)
__global__ void scan_add(int* __restrict__ rowptr, const int* __restrict__ aux,
                         const int* __restrict__ counts, int* __restrict__ cur,
                         float* __restrict__ dinv, int n, int E) {
    int g = blockIdx.x * blockDim.x + threadIdx.x;
    if (g < n) {
        int r = rowptr[g] + aux[g >> 10];
        rowptr[g] = r;
        cur[g] = r;
        dinv[g] = rsqrtf((float)counts[g] + 1.0f);
    }
    if (g == 0) rowptr[n] = E;
}

__global__ void fill_kernel(const int* __restrict__ src, const int* __restrict__ dst, int E,
                            int* __restrict__ cur, const float* __restrict__ dinv,
                            int* __restrict__ esrc, float* __restrict__ ewt) {
    int e = blockIdx.x * blockDim.x + threadIdx.x;
    if (e < E) {
        int d = dst[e];
        int s = src[e];
        int p = atomicAdd(&cur[d], 1);
        esrc[p] = s;
        ewt[p] = dinv[s] * dinv[d];
    }
}

// ================= both weight transposes + bf16 in one launch =================
__global__ void wt_all_kernel(const float* __restrict__ W1, const float* __restrict__ W2,
                              unsigned short* __restrict__ Wt1, unsigned short* __restrict__ Wt2) {
    int o = blockIdx.x * blockDim.x + threadIdx.x;
    if (o < 32 * 128) {
        int c = o / 32, k = o % 32;  // Wt1[c][k]
        Wt1[o] = (unsigned short)f2bf(W1[(size_t)k * 128 + c]);
    } else if (o < 32 * 128 + 128 * 128) {
        int o2 = o - 32 * 128;
        int c = o2 / 128, k = o2 % 128;
        Wt2[o2] = (unsigned short)f2bf(W2[(size_t)k * 128 + c]);
    }
}

// ================= MFMA GEMM: out[n,128] = norm(hb[n,K]) @ W, bf16 in/out =================
// STATS barrier is fine here: uniform work per block.
template <int K, bool NORM, bool STATS>
__global__ __launch_bounds__(256) void gemm_mfma(const unsigned short* __restrict__ hb,
                                                 const unsigned short* __restrict__ Wt,
                                                 const float* __restrict__ ss,
                                                 unsigned short* __restrict__ outb,
                                                 float* __restrict__ sums, int n) {
    int wid = (blockIdx.x * 256 + threadIdx.x) >> 6;
    int wv = (threadIdx.x >> 6);
    int lane = threadIdx.x & 63;
    int m = lane & 15;
    int qd = lane >> 4;
    int r0 = wid * 32;
    if (!STATS && r0 >= n) return;

    f32x4 acc[2][8];
#pragma unroll
    for (int rt = 0; rt < 2; rt++)
#pragma unroll
        for (int ct = 0; ct < 8; ct++) acc[rt][ct] = (f32x4){0.f, 0.f, 0.f, 0.f};

    if (r0 < n) {
#pragma unroll
        for (int q = 0; q < K / 32; q++) {
            int k0 = q * 32 + qd * 8;
            bf16x8 a[2];
#pragma unroll
            for (int rt = 0; rt < 2; rt++) {
                int r = r0 + rt * 16 + m;
                bf16x8 av = (bf16x8){0, 0, 0, 0, 0, 0, 0, 0};
                if (r < n) av = *(const bf16x8*)(hb + (size_t)r * K + k0);
                if (NORM) {
#pragma unroll
                    for (int j = 0; j < 8; j++) {
                        float f = bf2f((unsigned short)av[j]);
                        f = fmaxf(fmaf(f, ss[k0 + j], ss[K + k0 + j]), 0.f);
                        av[j] = f2bf(f);
                    }
                }
                a[rt] = av;
            }
#pragma unroll
            for (int ct = 0; ct < 8; ct++) {
                bf16x8 b = *(const bf16x8*)(Wt + (size_t)(ct * 16 + m) * K + k0);
                acc[0][ct] = __builtin_amdgcn_mfma_f32_16x16x32_bf16(a[0], b, acc[0][ct], 0, 0, 0);
                acc[1][ct] = __builtin_amdgcn_mfma_f32_16x16x32_bf16(a[1], b, acc[1][ct], 0, 0, 0);
            }
        }
#pragma unroll
        for (int rt = 0; rt < 2; rt++)
#pragma unroll
            for (int i = 0; i < 4; i++) {
                int r = r0 + rt * 16 + qd * 4 + i;
                if (r < n) {
#pragma unroll
                    for (int ct = 0; ct < 8; ct++)
                        outb[(size_t)r * 128 + ct * 16 + m] = (unsigned short)f2bf(acc[rt][ct][i]);
                }
            }
    }

    if (STATS) {
        __shared__ float ls[4][128], lq[4][128];
#pragma unroll
        for (int ct = 0; ct < 8; ct++) {
            float s = 0.f, q = 0.f;
#pragma unroll
            for (int rt = 0; rt < 2; rt++)
#pragma unroll
                for (int i = 0; i < 4; i++) {
                    float v = acc[rt][ct][i];
                    s += v;
                    q += v * v;
                }
            s += __shfl_xor(s, 16, 64);
            s += __shfl_xor(s, 32, 64);
            q += __shfl_xor(q, 16, 64);
            q += __shfl_xor(q, 32, 64);
            if (qd == 0) {
                ls[wv][ct * 16 + m] = s;
                lq[wv][ct * 16 + m] = q;
            }
        }
        __syncthreads();
        int t = threadIdx.x;
        if (t < 128) {
            atomicAdd(&sums[t], ls[0][t] + ls[1][t] + ls[2][t] + ls[3][t]);
        } else {
            int c = t - 128;
            atomicAdd(&sums[128 + c], lq[0][c] + lq[1][c] + lq[2][c] + lq[3][c]);
        }
    }
}

// GEMV, bf16 input, fused norm: out[n] = relu(hb[n,128]*S+T) @ W[128]
__global__ void gemv_norm_bf(const unsigned short* __restrict__ hb, const float* __restrict__ W,
                             const float* __restrict__ ss, float* __restrict__ out, int n) {
    int gid = blockIdx.x * blockDim.x + threadIdx.x;
    int wid = gid >> 6, lane = gid & 63;
    int nw = (gridDim.x * blockDim.x) >> 6;
    int c = lane * 2;
    float w0 = W[c], w1 = W[c + 1];
    float s0 = ss[c], s1 = ss[c + 1];
    float t0 = ss[128 + c], t1 = ss[128 + c + 1];
    for (int r = wid; r < n; r += nw) {
        ushort2 u = ((const ushort2*)(hb + (size_t)r * 128))[lane];
        float a = fmaxf(fmaf(bf2f(u.x), s0, t0), 0.f);
        float b = fmaxf(fmaf(bf2f(u.y), s1, t1), 0.f);
        float v = fmaf(a, w0, b * w1);
#pragma unroll
        for (int off = 32; off > 0; off >>= 1) v += __shfl_down(v, off, 64);
        if (lane == 0) out[r] = v;
    }
}

// ================= agg128: 8 nodes/block, 32 lanes/node, no barrier ==========
__global__ __launch_bounds__(256) void agg128_bf(const unsigned short* __restrict__ tmp,
                                                 const int* __restrict__ rowptr,
                                                 const int* __restrict__ esrc,
                                                 const float* __restrict__ ewt,
                                                 const float* __restrict__ dinv,
                                                 unsigned short* __restrict__ agg, int n) {
    int node = (blockIdx.x << 3) + (threadIdx.x >> 5);
    if (node >= n) return;
    int c4 = threadIdx.x & 31;  // ushort4 channel group
    float di = dinv[node];
    float d2 = di * di;
    ushort4 t = ((const ushort4*)tmp)[(size_t)node * 32 + c4];
    float a0 = bf2f(t.x) * d2, a1 = bf2f(t.y) * d2, a2 = bf2f(t.z) * d2, a3 = bf2f(t.w) * d2;
    int j = rowptr[node], je = rowptr[node + 1];
    for (; j + 8 <= je; j += 8) {
        int s[8];
        float w[8];
        ushort4 v[8];
#pragma unroll
        for (int k = 0; k < 8; k++) { s[k] = esrc[j + k]; w[k] = ewt[j + k]; }
#pragma unroll
        for (int k = 0; k < 8; k++) v[k] = ((const ushort4*)tmp)[(size_t)s[k] * 32 + c4];
#pragma unroll
        for (int k = 0; k < 8; k++) {
            a0 = fmaf(bf2f(v[k].x), w[k], a0);
            a1 = fmaf(bf2f(v[k].y), w[k], a1);
            a2 = fmaf(bf2f(v[k].z), w[k], a2);
            a3 = fmaf(bf2f(v[k].w), w[k], a3);
        }
    }
    if (j + 4 <= je) {
        int s[4];
        float w[4];
        ushort4 v[4];
#pragma unroll
        for (int k = 0; k < 4; k++) { s[k] = esrc[j + k]; w[k] = ewt[j + k]; }
#pragma unroll
        for (int k = 0; k < 4; k++) v[k] = ((const ushort4*)tmp)[(size_t)s[k] * 32 + c4];
#pragma unroll
        for (int k = 0; k < 4; k++) {
            a0 = fmaf(bf2f(v[k].x), w[k], a0);
            a1 = fmaf(bf2f(v[k].y), w[k], a1);
            a2 = fmaf(bf2f(v[k].z), w[k], a2);
            a3 = fmaf(bf2f(v[k].w), w[k], a3);
        }
        j += 4;
    }
    for (; j < je; j++) {
        int s = esrc[j];
        float w = ewt[j];
        ushort4 v = ((const ushort4*)tmp)[(size_t)s * 32 + c4];
        a0 = fmaf(bf2f(v.x), w, a0);
        a1 = fmaf(bf2f(v.y), w, a1);
        a2 = fmaf(bf2f(v.z), w, a2);
        a3 = fmaf(bf2f(v.w), w, a3);
    }
    ushort4 o;
    o.x = (unsigned short)f2bf(a0);
    o.y = (unsigned short)f2bf(a1);
    o.z = (unsigned short)f2bf(a2);
    o.w = (unsigned short)f2bf(a3);
    ((ushort4*)agg)[(size_t)node * 32 + c4] = o;
}

// ================= stats over bf16 matrix (separate streaming kernel, uniform work) =====
__global__ __launch_bounds__(256) void stats128_bf(const unsigned short* __restrict__ a,
                                                   float* __restrict__ sums, int n) {
    __shared__ float ls[16][128], lq[16][128];
    int t = threadIdx.x;
    int rg = t >> 4;        // row group 0..15
    int cg = t & 15;        // channel group: channels cg*8..cg*8+7
    float s[8], q[8];
#pragma unroll
    for (int k = 0; k < 8; k++) { s[k] = 0.f; q[k] = 0.f; }
    for (int r = blockIdx.x * 16 + rg; r < n; r += gridDim.x * 16) {
        u16x8 v = *(const u16x8*)(a + (size_t)r * 128 + cg * 8);
#pragma unroll
        for (int k = 0; k < 8; k++) {
            float f = bf2f(v[k]);
            s[k] += f;
            q[k] = fmaf(f, f, q[k]);
        }
    }
#pragma unroll
    for (int k = 0; k < 8; k++) {
        ls[rg][cg * 8 + k] = s[k];
        lq[rg][cg * 8 + k] = q[k];
    }
    __syncthreads();
    if (t < 128) {
        float v = 0.f;
#pragma unroll
        for (int i = 0; i < 16; i++) v += ls[i][t];
        atomicAdd(&sums[t], v);
    } else {
        int c = t - 128;
        float v = 0.f;
#pragma unroll
        for (int i = 0; i < 16; i++) v += lq[i][c];
        atomicAdd(&sums[128 + c], v);
    }
}

// ================= agg32: gather fp32 x directly, 8 lanes/node, float4 loads ============
__global__ __launch_bounds__(256) void agg32_f(const float* __restrict__ x,
                                               const int* __restrict__ rowptr,
                                               const int* __restrict__ esrc,
                                               const float* __restrict__ ewt,
                                               const float* __restrict__ dinv,
                                               unsigned short* __restrict__ xab, int n) {
    int g = threadIdx.x >> 3;   // 32 groups of 8 lanes
    int lane = threadIdx.x & 7;
    int node = blockIdx.x * 32 + g;
    if (node >= n) return;
    int co = lane << 2;
    float di = dinv[node];
    float d2 = di * di;
    float4 a = *(const float4*)(x + ((size_t)node << 5) + co);
    a.x *= d2; a.y *= d2; a.z *= d2; a.w *= d2;
    int j = rowptr[node], je = rowptr[node + 1];
    for (; j + 4 <= je; j += 4) {
        int s0 = esrc[j], s1 = esrc[j + 1], s2 = esrc[j + 2], s3 = esrc[j + 3];
        float w0 = ewt[j], w1 = ewt[j + 1], w2 = ewt[j + 2], w3 = ewt[j + 3];
        float4 v0 = *(const float4*)(x + ((size_t)s0 << 5) + co);
        float4 v1 = *(const float4*)(x + ((size_t)s1 << 5) + co);
        float4 v2 = *(const float4*)(x + ((size_t)s2 << 5) + co);
        float4 v3 = *(const float4*)(x + ((size_t)s3 << 5) + co);
        a.x = fmaf(v0.x, w0, a.x); a.y = fmaf(v0.y, w0, a.y);
        a.z = fmaf(v0.z, w0, a.z); a.w = fmaf(v0.w, w0, a.w);
        a.x = fmaf(v1.x, w1, a.x); a.y = fmaf(v1.y, w1, a.y);
        a.z = fmaf(v1.z, w1, a.z); a.w = fmaf(v1.w, w1, a.w);
        a.x = fmaf(v2.x, w2, a.x); a.y = fmaf(v2.y, w2, a.y);
        a.z = fmaf(v2.z, w2, a.z); a.w = fmaf(v2.w, w2, a.w);
        a.x = fmaf(v3.x, w3, a.x); a.y = fmaf(v3.y, w3, a.y);
        a.z = fmaf(v3.z, w3, a.z); a.w = fmaf(v3.w, w3, a.w);
    }
    for (; j < je; j++) {
        int s = esrc[j];
        float w = ewt[j];
        float4 v = *(const float4*)(x + ((size_t)s << 5) + co);
        a.x = fmaf(v.x, w, a.x); a.y = fmaf(v.y, w, a.y);
        a.z = fmaf(v.z, w, a.z); a.w = fmaf(v.w, w, a.w);
    }
    ushort4 o;
    o.x = (unsigned short)f2bf(a.x);
    o.y = (unsigned short)f2bf(a.y);
    o.z = (unsigned short)f2bf(a.z);
    o.w = (unsigned short)f2bf(a.w);
    ((ushort4*)(xab + ((size_t)node << 5)))[lane] = o;
}

// ================= agg1: 1 thread/node, per-wave NON-ATOMIC stats partials ==============
// Every wave writes its partial unconditionally (buffer is re-poisoned each launch).
__global__ void agg1_stats(const float* __restrict__ tmp, const int* __restrict__ rowptr,
                           const int* __restrict__ esrc, const float* __restrict__ ewt,
                           const float* __restrict__ dinv, float* __restrict__ out,
                           float* __restrict__ part, int n) {
    int i = blockIdx.x * blockDim.x + threadIdx.x;
    float acc = 0.f;
    if (i < n) {
        float di = dinv[i];
        acc = tmp[i] * di * di;
        int j = rowptr[i], je = rowptr[i + 1];
        for (; j + 4 <= je; j += 4) {
            int s0 = esrc[j], s1 = esrc[j + 1], s2 = esrc[j + 2], s3 = esrc[j + 3];
            float w0 = ewt[j], w1 = ewt[j + 1], w2 = ewt[j + 2], w3 = ewt[j + 3];
            float v0 = tmp[s0], v1 = tmp[s1], v2 = tmp[s2], v3 = tmp[s3];
            acc = fmaf(v0, w0, acc);
            acc = fmaf(v1, w1, acc);
            acc = fmaf(v2, w2, acc);
            acc = fmaf(v3, w3, acc);
        }
        for (; j < je; j++) acc = fmaf(tmp[esrc[j]], ewt[j], acc);
        out[i] = acc;
    }
    float s = acc, q = acc * acc;
#pragma unroll
    for (int off = 32; off > 0; off >>= 1) {
        s += __shfl_down(s, off, 64);
        q += __shfl_down(q, off, 64);
    }
    if ((threadIdx.x & 63) == 0) {
        int wgid = (blockIdx.x * blockDim.x + threadIdx.x) >> 6;
        part[2 * wgid] = s;
        part[2 * wgid + 1] = q;
    }
}

// reduce per-wave partials -> sums[0], sums[1]  (single block, uniform work)
__global__ __launch_bounds__(256) void reduce_part(const float* __restrict__ part,
                                                   float* __restrict__ sums, int nw) {
    __shared__ float ls[256], lq[256];
    int t = threadIdx.x;
    float s = 0.f, q = 0.f;
    for (int i = t; i < nw; i += 256) {
        s += part[2 * i];
        q += part[2 * i + 1];
    }
    ls[t] = s;
    lq[t] = q;
    __syncthreads();
    for (int off = 128; off > 0; off >>= 1) {
        if (t < off) {
            ls[t] += ls[t + off];
            lq[t] += lq[t + off];
        }
        __syncthreads();
    }
    if (t == 0) {
        sums[0] = ls[0];
        sums[1] = lq[0];
    }
}

// apply with inline C=1 finalize
__global__ void apply1_kernel(const float* __restrict__ sums, const float* __restrict__ g,
                              const float* __restrict__ lw, const float* __restrict__ lb,
                              const float* __restrict__ a, float* __restrict__ out, int n) {
    int i = blockIdx.x * blockDim.x + threadIdx.x;
    if (i >= n) return;
    float m = sums[0] / n;
    float v = sums[1] / n - m * m;
    v = v < 0.f ? 0.f : v;
    float bs = rsqrtf(v + EPS) * g[0];
    float vz = v * bs * bs;
    float t = bs * rsqrtf(vz + EPS);
    float GV = v * t * t;
    float S = t * rsqrtf(GV + EPS) * lw[0];
    float T = lb[0] - m * S;
    out[i] = fmaf(a[i], S, T);
}

// ================= finalize: fused BN->IN->LN (C=128) =================
template <int C>
__global__ void finalize_kernel(const float* __restrict__ sums, const float* __restrict__ g,
                                const float* __restrict__ lw, const float* __restrict__ lb,
                                float* __restrict__ ss, int n) {
    __shared__ float vt2[C];
    int c = threadIdx.x;
    float m = sums[c] / n;
    float v = sums[C + c] / n - m * m;
    v = v < 0.f ? 0.f : v;
    float gc = g[c];
    float bs = rsqrtf(v + EPS) * gc;
    float vz = v * bs * bs;
    float t = bs * rsqrtf(vz + EPS);
    vt2[c] = v * t * t;
    __syncthreads();
    if (c == 0) {
        float gv = 0.f;
        for (int i = 0; i < C; i++) gv += vt2[i];
        vt2[0] = gv / C;
    }
    __syncthreads();
    float GV = vt2[0];
    float S = t * rsqrtf(GV + EPS) * lw[c];
    ss[c] = S;
    ss[C + c] = lb[c] - m * S;
}

extern "C" void kernel_launch(void* const* d_in, const int* in_sizes, int n_in,
                              void* d_out, int out_size, void* d_ws, size_t ws_size,
                              hipStream_t stream) {
    const float* x = (const float*)d_in[0];
    const int* ei = (const int*)d_in[1];
    int n = in_sizes[0] / 32;
    int E = in_sizes[1] / 2;
    const int* src = ei;
    const int* dstp = ei + E;
    const float* W1 = (const float*)d_in[2];
    const float* g1 = (const float*)d_in[4];
    const float* lw1 = (const float*)d_in[6];
    const float* lb1 = (const float*)d_in[7];
    const float* W2 = (const float*)d_in[8];
    const float* g2 = (const float*)d_in[10];
    const float* lw2 = (const float*)d_in[12];
    const float* lb2 = (const float*)d_in[13];
    const float* W3 = (const float*)d_in[14];
    const float* g3 = (const float*)d_in[16];
    const float* lw3 = (const float*)d_in[18];
    const float* lb3 = (const float*)d_in[19];
    float* out = (float*)d_out;

    // workspace layout (16B-aligned chunks)
    char* p = (char*)d_ws;
    int* counts = (int*)p;             p += (size_t)n * 4;
    int* cur = (int*)p;                p += (size_t)n * 4;
    int* rowptr = (int*)p;             p += (size_t)(n + 4) * 4;
    int* aux = (int*)p;                p += 128 * 4;
    int* esrc = (int*)p;               p += (size_t)E * 4;
    float* ewt = (float*)p;            p += (size_t)E * 4;
    float* dinv = (float*)p;           p += (size_t)n * 4;
    unsigned short* Wt1 = (unsigned short*)p;  p += 128 * 32 * 2;
    unsigned short* Wt2 = (unsigned short*)p;  p += 128 * 128 * 2;
    unsigned short* xa = (unsigned short*)p;   p += (size_t)n * 32 * 2;
    unsigned short* h1 = (unsigned short*)p;   p += (size_t)n * 128 * 2;
    unsigned short* t2 = (unsigned short*)p;   p += (size_t)n * 128 * 2;
    unsigned short* a2 = (unsigned short*)p;   p += (size_t)n * 128 * 2;
    float* t3 = (float*)p;             p += (size_t)n * 4;
    float* a3 = (float*)p;             p += (size_t)n * 4;
    float* sums1 = (float*)p;          p += 256 * 4;
    float* sums2 = (float*)p;          p += 256 * 4;
    float* sums3 = (float*)p;          p += 4 * 4;
    float* ss1 = (float*)p;            p += 256 * 4;
    float* ss2 = (float*)p;            p += 256 * 4;
    float* part3 = (float*)p;          p += ((size_t)(n + 255) / 256) * 4 * 2 * 4;

    int B = (n + 1023) / 1024;

    // ---- CSR build + prep ----
    hipMemsetAsync(counts, 0, (size_t)n * 4, stream);
    hipMemsetAsync(sums1, 0, 516 * 4, stream);
    hist_kernel<<<(E + 255) / 256, 256, 0, stream>>>(dstp, E, counts);
    scan_part<<<B, 1024, 0, stream>>>(counts, rowptr, aux, n);
    scan_aux<<<1, 128, 0, stream>>>(aux, B);
    scan_add<<<(n + 255) / 256, 256, 0, stream>>>(rowptr, aux, counts, cur, dinv, n, E);
    fill_kernel<<<(E + 255) / 256, 256, 0, stream>>>(src, dstp, E, cur, dinv, esrc, ewt);
    wt_all_kernel<<<(32 * 128 + 128 * 128 + 255) / 256, 256, 0, stream>>>(W1, W2, Wt1, Wt2);

    int mblk = ((n + 31) / 32 + 3) / 4;

    // ---- layer 1: agg(x) fp32->bf16 in 32-dim, MFMA GEMM 32->128 with fused stats ----
    agg32_f<<<(n + 31) / 32, 256, 0, stream>>>(x, rowptr, esrc, ewt, dinv, xa, n);
    gemm_mfma<32, false, true><<<mblk, 256, 0, stream>>>(xa, Wt1, nullptr, h1, sums1, n);
    finalize_kernel<128><<<1, 128, 0, stream>>>(sums1, g1, lw1, lb1, ss1, n);

    // ---- layer 2: MFMA GEMM 128->128 (norm fused), agg (no barrier), separate stats ----
    gemm_mfma<128, true, false><<<mblk, 256, 0, stream>>>(h1, Wt2, ss1, t2, nullptr, n);
    agg128_bf<<<(n + 7) / 8, 256, 0, stream>>>(t2, rowptr, esrc, ewt, dinv, a2, n);
    stats128_bf<<<512, 256, 0, stream>>>(a2, sums2, n);
    finalize_kernel<128><<<1, 128, 0, stream>>>(sums2, g2, lw2, lb2, ss2, n);

    // ---- layer 3: gemv (norm fused), agg with non-atomic partials, reduce, apply ----
    int ablk1 = (n + 255) / 256;
    gemv_norm_bf<<<1024, 256, 0, stream>>>(a2, W3, ss2, t3, n);
    agg1_stats<<<ablk1, 256, 0, stream>>>(t3, rowptr, esrc, ewt, dinv, a3, part3, n);
    reduce_part<<<1, 256, 0, stream>>>(part3, sums3, ablk1 * 4);
    apply1_kernel<<<(n + 255) / 256, 256, 0, stream>>>(sums3, g3, lw3, lb3, a3, out, n);
}

// Round 11
// 307.696 us; speedup vs baseline: 1.5320x; 1.0106x over previous
//
#include <hip/hip_runtime.h>
#include <cstddef>

#define EPS 1e-5f

typedef __attribute__((ext_vector_type(8))) short bf16x8;
typedef __attribute__((ext_vector_type(8))) unsigned short u16x8;
typedef __attribute__((ext_vector_type(4))) float f32x4;

__device__ inline short f2bf(float f) {
    union { float f; unsigned u; } v;
    v.f = f;
    unsigned r = v.u + 0x7fff + ((v.u >> 16) & 1);  // RNE
    return (short)(r >> 16);
}
__device__ inline float bf2f(unsigned short s) {
    union { unsigned u; float f; } v;
    v.u = ((unsigned)s) << 16;
    return v.f;
}

// ================= prep: zero counts/sums/scan-state + both weight transposes ===========
__global__ void prep_kernel(const float* __restrict__ W1, const float* __restrict__ W2,
                            unsigned short* __restrict__ Wt1, unsigned short* __restrict__ Wt2,
                            int* __restrict__ counts, float* __restrict__ sums,
                            unsigned long long* __restrict__ state, int* __restrict__ ticket,
                            int n) {
    int o = blockIdx.x * blockDim.x + threadIdx.x;
    if (o < n) counts[o] = 0;
    if (o < 516) sums[o] = 0.f;
    if (o < 128) state[o] = 0ULL;
    if (o == 0) *ticket = 0;
    if (o < 32 * 128) {
        int c = o / 32, k = o % 32;  // Wt1[c][k]
        Wt1[o] = (unsigned short)f2bf(W1[(size_t)k * 128 + c]);
    } else if (o < 32 * 128 + 128 * 128) {
        int o2 = o - 32 * 128;
        int c = o2 / 128, k = o2 % 128;
        Wt2[o2] = (unsigned short)f2bf(W2[(size_t)k * 128 + c]);
    }
}

// ================= CSR build (by dst) =================
__global__ void hist_kernel(const int* __restrict__ dst, int E, int* __restrict__ counts) {
    int i = blockIdx.x * blockDim.x + threadIdx.x;
    if (i < E) atomicAdd(&counts[dst[i]], 1);
}

// single-kernel exclusive scan (decoupled lookback) + rowptr/cur/dinv production.
// state[b] = (flag<<32)|value; flag 1=aggregate ready, 2=inclusive ready.
__global__ __launch_bounds__(1024) void scan_lookback(const int* __restrict__ counts,
                                                      int* __restrict__ rowptr,
                                                      int* __restrict__ cur,
                                                      float* __restrict__ dinv,
                                                      unsigned long long* __restrict__ state,
                                                      int* __restrict__ ticket, int n, int E) {
    __shared__ int sh[1024];
    __shared__ int sbid, sexcl;
    int t = threadIdx.x;
    if (t == 0) sbid = atomicAdd(ticket, 1);
    __syncthreads();
    int bid = sbid;
    int g = bid * 1024 + t;
    int v = (g < n) ? counts[g] : 0;
    sh[t] = v;
    __syncthreads();
    for (int off = 1; off < 1024; off <<= 1) {
        int add = (t >= off) ? sh[t - off] : 0;
        __syncthreads();
        sh[t] += add;
        __syncthreads();
    }
    int total = sh[1023];
    if (t == 0) {
        if (bid == 0) {
            atomicExch(&state[0], (2ULL << 32) | (unsigned)total);
            sexcl = 0;
        } else {
            atomicExch(&state[bid], (1ULL << 32) | (unsigned)total);
            int excl = 0;
            int j = bid - 1;
            while (true) {
                unsigned long long s;
                do { s = atomicAdd(&state[j], 0ULL); } while ((s >> 32) == 0);
                excl += (int)(s & 0xffffffffULL);
                if ((s >> 32) == 2ULL) break;
                j--;
            }
            atomicExch(&state[bid], (2ULL << 32) | (unsigned)(excl + total));
            sexcl = excl;
        }
    }
    __syncthreads();
    int excl = sexcl;
    if (g < n) {
        int r = excl + sh[t] - v;  // exclusive prefix
        rowptr[g] = r;
        cur[g] = r;
        dinv[g] = rsqrtf((float)counts[g] + 1.0f);
    }
    if (g == 0) rowptr[n] = E;
}

__global__ void fill_kernel(const int* __restrict__ src, const int* __restrict__ dst, int E,
                            int* __restrict__ cur, const float* __restrict__ dinv,
                            int* __restrict__ esrc, float* __restrict__ ewt) {
    int e = blockIdx.x * blockDim.x + threadIdx.x;
    if (e < E) {
        int d = dst[e];
        int s = src[e];
        int p = atomicAdd(&cur[d], 1);
        esrc[p] = s;
        ewt[p] = dinv[s] * dinv[d];
    }
}

// ================= MFMA GEMM: out[n,128] = norm(hb[n,K]) @ W, bf16 in/out =================
// STATS barrier is fine here: uniform work per block.
template <int K, bool NORM, bool STATS>
__global__ __launch_bounds__(256) void gemm_mfma(const unsigned short* __restrict__ hb,
                                                 const unsigned short* __restrict__ Wt,
                                                 const float* __restrict__ ss,
                                                 unsigned short* __restrict__ outb,
                                                 float* __restrict__ sums, int n) {
    int wid = (blockIdx.x * 256 + threadIdx.x) >> 6;
    int wv = (threadIdx.x >> 6);
    int lane = threadIdx.x & 63;
    int m = lane & 15;
    int qd = lane >> 4;
    int r0 = wid * 32;
    if (!STATS && r0 >= n) return;

    f32x4 acc[2][8];
#pragma unroll
    for (int rt = 0; rt < 2; rt++)
#pragma unroll
        for (int ct = 0; ct < 8; ct++) acc[rt][ct] = (f32x4){0.f, 0.f, 0.f, 0.f};

    if (r0 < n) {
#pragma unroll
        for (int q = 0; q < K / 32; q++) {
            int k0 = q * 32 + qd * 8;
            bf16x8 a[2];
#pragma unroll
            for (int rt = 0; rt < 2; rt++) {
                int r = r0 + rt * 16 + m;
                bf16x8 av = (bf16x8){0, 0, 0, 0, 0, 0, 0, 0};
                if (r < n) av = *(const bf16x8*)(hb + (size_t)r * K + k0);
                if (NORM) {
#pragma unroll
                    for (int j = 0; j < 8; j++) {
                        float f = bf2f((unsigned short)av[j]);
                        f = fmaxf(fmaf(f, ss[k0 + j], ss[K + k0 + j]), 0.f);
                        av[j] = f2bf(f);
                    }
                }
                a[rt] = av;
            }
#pragma unroll
            for (int ct = 0; ct < 8; ct++) {
                bf16x8 b = *(const bf16x8*)(Wt + (size_t)(ct * 16 + m) * K + k0);
                acc[0][ct] = __builtin_amdgcn_mfma_f32_16x16x32_bf16(a[0], b, acc[0][ct], 0, 0, 0);
                acc[1][ct] = __builtin_amdgcn_mfma_f32_16x16x32_bf16(a[1], b, acc[1][ct], 0, 0, 0);
            }
        }
#pragma unroll
        for (int rt = 0; rt < 2; rt++)
#pragma unroll
            for (int i = 0; i < 4; i++) {
                int r = r0 + rt * 16 + qd * 4 + i;
                if (r < n) {
#pragma unroll
                    for (int ct = 0; ct < 8; ct++)
                        outb[(size_t)r * 128 + ct * 16 + m] = (unsigned short)f2bf(acc[rt][ct][i]);
                }
            }
    }

    if (STATS) {
        __shared__ float ls[4][128], lq[4][128];
#pragma unroll
        for (int ct = 0; ct < 8; ct++) {
            float s = 0.f, q = 0.f;
#pragma unroll
            for (int rt = 0; rt < 2; rt++)
#pragma unroll
                for (int i = 0; i < 4; i++) {
                    float v = acc[rt][ct][i];
                    s += v;
                    q += v * v;
                }
            s += __shfl_xor(s, 16, 64);
            s += __shfl_xor(s, 32, 64);
            q += __shfl_xor(q, 16, 64);
            q += __shfl_xor(q, 32, 64);
            if (qd == 0) {
                ls[wv][ct * 16 + m] = s;
                lq[wv][ct * 16 + m] = q;
            }
        }
        __syncthreads();
        int t = threadIdx.x;
        if (t < 128) {
            atomicAdd(&sums[t], ls[0][t] + ls[1][t] + ls[2][t] + ls[3][t]);
        } else {
            int c = t - 128;
            atomicAdd(&sums[128 + c], lq[0][c] + lq[1][c] + lq[2][c] + lq[3][c]);
        }
    }
}

// GEMV, bf16 input, fused norm: out[n] = relu(hb[n,128]*S+T) @ W[128]
__global__ void gemv_norm_bf(const unsigned short* __restrict__ hb, const float* __restrict__ W,
                             const float* __restrict__ ss, float* __restrict__ out, int n) {
    int gid = blockIdx.x * blockDim.x + threadIdx.x;
    int wid = gid >> 6, lane = gid & 63;
    int nw = (gridDim.x * blockDim.x) >> 6;
    int c = lane * 2;
    float w0 = W[c], w1 = W[c + 1];
    float s0 = ss[c], s1 = ss[c + 1];
    float t0 = ss[128 + c], t1 = ss[128 + c + 1];
    for (int r = wid; r < n; r += nw) {
        ushort2 u = ((const ushort2*)(hb + (size_t)r * 128))[lane];
        float a = fmaxf(fmaf(bf2f(u.x), s0, t0), 0.f);
        float b = fmaxf(fmaf(bf2f(u.y), s1, t1), 0.f);
        float v = fmaf(a, w0, b * w1);
#pragma unroll
        for (int off = 32; off > 0; off >>= 1) v += __shfl_down(v, off, 64);
        if (lane == 0) out[r] = v;
    }
}

// ================= agg128: 16 nodes/block, 16 lanes/node, u16x8, no barrier =============
__global__ __launch_bounds__(256) void agg128_bf(const unsigned short* __restrict__ tmp,
                                                 const int* __restrict__ rowptr,
                                                 const int* __restrict__ esrc,
                                                 const float* __restrict__ ewt,
                                                 const float* __restrict__ dinv,
                                                 unsigned short* __restrict__ agg, int n) {
    int node = (blockIdx.x << 4) + (threadIdx.x >> 4);
    if (node >= n) return;
    int co = (threadIdx.x & 15) << 3;  // 8-channel offset
    float di = dinv[node];
    float d2 = di * di;
    u16x8 t = *(const u16x8*)(tmp + ((size_t)node << 7) + co);
    float acc[8];
#pragma unroll
    for (int k = 0; k < 8; k++) acc[k] = bf2f(t[k]) * d2;
    int j = rowptr[node], je = rowptr[node + 1];
    for (; j + 8 <= je; j += 8) {
        int s[8];
        float w[8];
        u16x8 v[8];
#pragma unroll
        for (int k = 0; k < 8; k++) { s[k] = esrc[j + k]; w[k] = ewt[j + k]; }
#pragma unroll
        for (int k = 0; k < 8; k++) v[k] = *(const u16x8*)(tmp + ((size_t)s[k] << 7) + co);
#pragma unroll
        for (int k = 0; k < 8; k++)
#pragma unroll
            for (int c = 0; c < 8; c++) acc[c] = fmaf(bf2f(v[k][c]), w[k], acc[c]);
    }
    if (j + 4 <= je) {
        int s[4];
        float w[4];
        u16x8 v[4];
#pragma unroll
        for (int k = 0; k < 4; k++) { s[k] = esrc[j + k]; w[k] = ewt[j + k]; }
#pragma unroll
        for (int k = 0; k < 4; k++) v[k] = *(const u16x8*)(tmp + ((size_t)s[k] << 7) + co);
#pragma unroll
        for (int k = 0; k < 4; k++)
#pragma unroll
            for (int c = 0; c < 8; c++) acc[c] = fmaf(bf2f(v[k][c]), w[k], acc[c]);
        j += 4;
    }
    for (; j < je; j++) {
        int s = esrc[j];
        float w = ewt[j];
        u16x8 v = *(const u16x8*)(tmp + ((size_t)s << 7) + co);
#pragma unroll
        for (int c = 0; c < 8; c++) acc[c] = fmaf(bf2f(v[c]), w, acc[c]);
    }
    u16x8 o;
#pragma unroll
    for (int k = 0; k < 8; k++) o[k] = (unsigned short)f2bf(acc[k]);
    *(u16x8*)(agg + ((size_t)node << 7) + co) = o;
}

// ================= stats over bf16 matrix (separate streaming kernel, uniform work) =====
__global__ __launch_bounds__(256) void stats128_bf(const unsigned short* __restrict__ a,
                                                   float* __restrict__ sums, int n) {
    __shared__ float ls[16][128], lq[16][128];
    int t = threadIdx.x;
    int rg = t >> 4;
    int cg = t & 15;
    float s[8], q[8];
#pragma unroll
    for (int k = 0; k < 8; k++) { s[k] = 0.f; q[k] = 0.f; }
    for (int r = blockIdx.x * 16 + rg; r < n; r += gridDim.x * 16) {
        u16x8 v = *(const u16x8*)(a + (size_t)r * 128 + cg * 8);
#pragma unroll
        for (int k = 0; k < 8; k++) {
            float f = bf2f(v[k]);
            s[k] += f;
            q[k] = fmaf(f, f, q[k]);
        }
    }
#pragma unroll
    for (int k = 0; k < 8; k++) {
        ls[rg][cg * 8 + k] = s[k];
        lq[rg][cg * 8 + k] = q[k];
    }
    __syncthreads();
    if (t < 128) {
        float v = 0.f;
#pragma unroll
        for (int i = 0; i < 16; i++) v += ls[i][t];
        atomicAdd(&sums[t], v);
    } else {
        int c = t - 128;
        float v = 0.f;
#pragma unroll
        for (int i = 0; i < 16; i++) v += lq[i][c];
        atomicAdd(&sums[128 + c], v);
    }
}

// ================= agg32: gather fp32 x directly, 8 lanes/node, float4 loads ============
__global__ __launch_bounds__(256) void agg32_f(const float* __restrict__ x,
                                               const int* __restrict__ rowptr,
                                               const int* __restrict__ esrc,
                                               const float* __restrict__ ewt,
                                               const float* __restrict__ dinv,
                                               unsigned short* __restrict__ xab, int n) {
    int g = threadIdx.x >> 3;
    int lane = threadIdx.x & 7;
    int node = blockIdx.x * 32 + g;
    if (node >= n) return;
    int co = lane << 2;
    float di = dinv[node];
    float d2 = di * di;
    float4 a = *(const float4*)(x + ((size_t)node << 5) + co);
    a.x *= d2; a.y *= d2; a.z *= d2; a.w *= d2;
    int j = rowptr[node], je = rowptr[node + 1];
    for (; j + 4 <= je; j += 4) {
        int s0 = esrc[j], s1 = esrc[j + 1], s2 = esrc[j + 2], s3 = esrc[j + 3];
        float w0 = ewt[j], w1 = ewt[j + 1], w2 = ewt[j + 2], w3 = ewt[j + 3];
        float4 v0 = *(const float4*)(x + ((size_t)s0 << 5) + co);
        float4 v1 = *(const float4*)(x + ((size_t)s1 << 5) + co);
        float4 v2 = *(const float4*)(x + ((size_t)s2 << 5) + co);
        float4 v3 = *(const float4*)(x + ((size_t)s3 << 5) + co);
        a.x = fmaf(v0.x, w0, a.x); a.y = fmaf(v0.y, w0, a.y);
        a.z = fmaf(v0.z, w0, a.z); a.w = fmaf(v0.w, w0, a.w);
        a.x = fmaf(v1.x, w1, a.x); a.y = fmaf(v1.y, w1, a.y);
        a.z = fmaf(v1.z, w1, a.z); a.w = fmaf(v1.w, w1, a.w);
        a.x = fmaf(v2.x, w2, a.x); a.y = fmaf(v2.y, w2, a.y);
        a.z = fmaf(v2.z, w2, a.z); a.w = fmaf(v2.w, w2, a.w);
        a.x = fmaf(v3.x, w3, a.x); a.y = fmaf(v3.y, w3, a.y);
        a.z = fmaf(v3.z, w3, a.z); a.w = fmaf(v3.w, w3, a.w);
    }
    for (; j < je; j++) {
        int s = esrc[j];
        float w = ewt[j];
        float4 v = *(const float4*)(x + ((size_t)s << 5) + co);
        a.x = fmaf(v.x, w, a.x); a.y = fmaf(v.y, w, a.y);
        a.z = fmaf(v.z, w, a.z); a.w = fmaf(v.w, w, a.w);
    }
    ushort4 o;
    o.x = (unsigned short)f2bf(a.x);
    o.y = (unsigned short)f2bf(a.y);
    o.z = (unsigned short)f2bf(a.z);
    o.w = (unsigned short)f2bf(a.w);
    ((ushort4*)(xab + ((size_t)node << 5)))[lane] = o;
}

// ================= agg1: 1 thread/node, per-wave NON-ATOMIC stats partials ==============
__global__ void agg1_stats(const float* __restrict__ tmp, const int* __restrict__ rowptr,
                           const int* __restrict__ esrc, const float* __restrict__ ewt,
                           const float* __restrict__ dinv, float* __restrict__ out,
                           float* __restrict__ part, int n) {
    int i = blockIdx.x * blockDim.x + threadIdx.x;
    float acc = 0.f;
    if (i < n) {
        float di = dinv[i];
        acc = tmp[i] * di * di;
        int j = rowptr[i], je = rowptr[i + 1];
        for (; j + 4 <= je; j += 4) {
            int s0 = esrc[j], s1 = esrc[j + 1], s2 = esrc[j + 2], s3 = esrc[j + 3];
            float w0 = ewt[j], w1 = ewt[j + 1], w2 = ewt[j + 2], w3 = ewt[j + 3];
            float v0 = tmp[s0], v1 = tmp[s1], v2 = tmp[s2], v3 = tmp[s3];
            acc = fmaf(v0, w0, acc);
            acc = fmaf(v1, w1, acc);
            acc = fmaf(v2, w2, acc);
            acc = fmaf(v3, w3, acc);
        }
        for (; j < je; j++) acc = fmaf(tmp[esrc[j]], ewt[j], acc);
        out[i] = acc;
    }
    float s = acc, q = acc * acc;
#pragma unroll
    for (int off = 32; off > 0; off >>= 1) {
        s += __shfl_down(s, off, 64);
        q += __shfl_down(q, off, 64);
    }
    if ((threadIdx.x & 63) == 0) {
        int wgid = (blockIdx.x * blockDim.x + threadIdx.x) >> 6;
        part[2 * wgid] = s;
        part[2 * wgid + 1] = q;
    }
}

__global__ __launch_bounds__(256) void reduce_part(const float* __restrict__ part,
                                                   float* __restrict__ sums, int nw) {
    __shared__ float ls[256], lq[256];
    int t = threadIdx.x;
    float s = 0.f, q = 0.f;
    for (int i = t; i < nw; i += 256) {
        s += part[2 * i];
        q += part[2 * i + 1];
    }
    ls[t] = s;
    lq[t] = q;
    __syncthreads();
    for (int off = 128; off > 0; off >>= 1) {
        if (t < off) {
            ls[t] += ls[t + off];
            lq[t] += lq[t + off];
        }
        __syncthreads();
    }
    if (t == 0) {
        sums[0] = ls[0];
        sums[1] = lq[0];
    }
}

__global__ void apply1_kernel(const float* __restrict__ sums, const float* __restrict__ g,
                              const float* __restrict__ lw, const float* __restrict__ lb,
                              const float* __restrict__ a, float* __restrict__ out, int n) {
    int i = blockIdx.x * blockDim.x + threadIdx.x;
    if (i >= n) return;
    float m = sums[0] / n;
    float v = sums[1] / n - m * m;
    v = v < 0.f ? 0.f : v;
    float bs = rsqrtf(v + EPS) * g[0];
    float vz = v * bs * bs;
    float t = bs * rsqrtf(vz + EPS);
    float GV = v * t * t;
    float S = t * rsqrtf(GV + EPS) * lw[0];
    float T = lb[0] - m * S;
    out[i] = fmaf(a[i], S, T);
}

// ================= finalize: fused BN->IN->LN (C=128) =================
template <int C>
__global__ void finalize_kernel(const float* __restrict__ sums, const float* __restrict__ g,
                                const float* __restrict__ lw, const float* __restrict__ lb,
                                float* __restrict__ ss, int n) {
    __shared__ float vt2[C];
    int c = threadIdx.x;
    float m = sums[c] / n;
    float v = sums[C + c] / n - m * m;
    v = v < 0.f ? 0.f : v;
    float gc = g[c];
    float bs = rsqrtf(v + EPS) * gc;
    float vz = v * bs * bs;
    float t = bs * rsqrtf(vz + EPS);
    vt2[c] = v * t * t;
    __syncthreads();
    if (c == 0) {
        float gv = 0.f;
        for (int i = 0; i < C; i++) gv += vt2[i];
        vt2[0] = gv / C;
    }
    __syncthreads();
    float GV = vt2[0];
    float S = t * rsqrtf(GV + EPS) * lw[c];
    ss[c] = S;
    ss[C + c] = lb[c] - m * S;
}

extern "C" void kernel_launch(void* const* d_in, const int* in_sizes, int n_in,
                              void* d_out, int out_size, void* d_ws, size_t ws_size,
                              hipStream_t stream) {
    const float* x = (const float*)d_in[0];
    const int* ei = (const int*)d_in[1];
    int n = in_sizes[0] / 32;
    int E = in_sizes[1] / 2;
    const int* src = ei;
    const int* dstp = ei + E;
    const float* W1 = (const float*)d_in[2];
    const float* g1 = (const float*)d_in[4];
    const float* lw1 = (const float*)d_in[6];
    const float* lb1 = (const float*)d_in[7];
    const float* W2 = (const float*)d_in[8];
    const float* g2 = (const float*)d_in[10];
    const float* lw2 = (const float*)d_in[12];
    const float* lb2 = (const float*)d_in[13];
    const float* W3 = (const float*)d_in[14];
    const float* g3 = (const float*)d_in[16];
    const float* lw3 = (const float*)d_in[18];
    const float* lb3 = (const float*)d_in[19];
    float* out = (float*)d_out;

    // workspace layout (16B-aligned chunks)
    char* p = (char*)d_ws;
    int* counts = (int*)p;             p += (size_t)n * 4;
    int* cur = (int*)p;                p += (size_t)n * 4;
    int* rowptr = (int*)p;             p += (size_t)(n + 4) * 4;
    unsigned long long* state = (unsigned long long*)p;  p += 128 * 8;
    int* ticket = (int*)p;             p += 4 * 4;
    int* esrc = (int*)p;               p += (size_t)E * 4;
    float* ewt = (float*)p;            p += (size_t)E * 4;
    float* dinv = (float*)p;           p += (size_t)n * 4;
    unsigned short* Wt1 = (unsigned short*)p;  p += 128 * 32 * 2;
    unsigned short* Wt2 = (unsigned short*)p;  p += 128 * 128 * 2;
    unsigned short* xa = (unsigned short*)p;   p += (size_t)n * 32 * 2;
    unsigned short* h1 = (unsigned short*)p;   p += (size_t)n * 128 * 2;
    unsigned short* t2 = (unsigned short*)p;   p += (size_t)n * 128 * 2;
    unsigned short* a2 = (unsigned short*)p;   p += (size_t)n * 128 * 2;
    float* t3 = (float*)p;             p += (size_t)n * 4;
    float* a3 = (float*)p;             p += (size_t)n * 4;
    float* sums1 = (float*)p;          p += 256 * 4;
    float* sums2 = (float*)p;          p += 256 * 4;
    float* sums3 = (float*)p;          p += 4 * 4;
    float* ss1 = (float*)p;            p += 256 * 4;
    float* ss2 = (float*)p;            p += 256 * 4;
    float* part3 = (float*)p;          p += ((size_t)(n + 255) / 256) * 4 * 2 * 4;

    int B = (n + 1023) / 1024;  // scan blocks (<=128 for n<=131072)

    // ---- prep + CSR build ----
    prep_kernel<<<(n + 255) / 256, 256, 0, stream>>>(W1, W2, Wt1, Wt2, counts, sums1,
                                                     state, ticket, n);
    hist_kernel<<<(E + 255) / 256, 256, 0, stream>>>(dstp, E, counts);
    scan_lookback<<<B, 1024, 0, stream>>>(counts, rowptr, cur, dinv, state, ticket, n, E);
    fill_kernel<<<(E + 255) / 256, 256, 0, stream>>>(src, dstp, E, cur, dinv, esrc, ewt);

    int mblk = ((n + 31) / 32 + 3) / 4;

    // ---- layer 1: agg(x) fp32->bf16 in 32-dim, MFMA GEMM 32->128 with fused stats ----
    agg32_f<<<(n + 31) / 32, 256, 0, stream>>>(x, rowptr, esrc, ewt, dinv, xa, n);
    gemm_mfma<32, false, true><<<mblk, 256, 0, stream>>>(xa, Wt1, nullptr, h1, sums1, n);
    finalize_kernel<128><<<1, 128, 0, stream>>>(sums1, g1, lw1, lb1, ss1, n);

    // ---- layer 2: MFMA GEMM 128->128 (norm fused), agg (no barrier), separate stats ----
    gemm_mfma<128, true, false><<<mblk, 256, 0, stream>>>(h1, Wt2, ss1, t2, nullptr, n);
    agg128_bf<<<(n + 15) / 16, 256, 0, stream>>>(t2, rowptr, esrc, ewt, dinv, a2, n);
    stats128_bf<<<512, 256, 0, stream>>>(a2, sums2, n);
    finalize_kernel<128><<<1, 128, 0, stream>>>(sums2, g2, lw2, lb2, ss2, n);

    // ---- layer 3: gemv (norm fused), agg with non-atomic partials, reduce, apply ----
    int ablk1 = (n + 255) / 256;
    gemv_norm_bf<<<1024, 256, 0, stream>>>(a2, W3, ss2, t3, n);
    agg1_stats<<<ablk1, 256, 0, stream>>>(t3, rowptr, esrc, ewt, dinv, a3, part3, n);
    reduce_part<<<1, 256, 0, stream>>>(part3, sums3, ablk1 * 4);
    apply1_kernel<<<(n + 255) / 256, 256, 0, stream>>>(sums3, g3, lw3, lb3, a3, out, n);
}

// Round 12
// 300.791 us; speedup vs baseline: 1.5671x; 1.0230x over previous
//
#include <hip/hip_runtime.h>
#include <cstddef>

#define EPS 1e-5f

typedef __attribute__((ext_vector_type(8))) short bf16x8;
typedef __attribute__((ext_vector_type(8))) unsigned short u16x8;
typedef __attribute__((ext_vector_type(4))) float f32x4;

__device__ inline short f2bf(float f) {
    union { float f; unsigned u; } v;
    v.f = f;
    unsigned r = v.u + 0x7fff + ((v.u >> 16) & 1);  // RNE
    return (short)(r >> 16);
}
__device__ inline float bf2f(unsigned short s) {
    union { unsigned u; float f; } v;
    v.u = ((unsigned)s) << 16;
    return v.f;
}

// ================= prep: zero counts/sums/scan-state + both weight transposes ===========
__global__ void prep_kernel(const float* __restrict__ W1, const float* __restrict__ W2,
                            unsigned short* __restrict__ Wt1, unsigned short* __restrict__ Wt2,
                            int* __restrict__ counts, float* __restrict__ sums,
                            unsigned long long* __restrict__ state, int* __restrict__ ticket,
                            int n) {
    int o = blockIdx.x * blockDim.x + threadIdx.x;
    if (o < n) counts[o] = 0;
    if (o < 512) sums[o] = 0.f;
    if (o < 128) state[o] = 0ULL;
    if (o == 0) *ticket = 0;
    if (o < 32 * 128) {
        int c = o / 32, k = o % 32;  // Wt1[c][k]
        Wt1[o] = (unsigned short)f2bf(W1[(size_t)k * 128 + c]);
    } else if (o < 32 * 128 + 128 * 128) {
        int o2 = o - 32 * 128;
        int c = o2 / 128, k = o2 % 128;
        Wt2[o2] = (unsigned short)f2bf(W2[(size_t)k * 128 + c]);
    }
}

// ================= CSR build (by dst) =================
__global__ void hist_kernel(const int* __restrict__ dst, int E, int* __restrict__ counts) {
    int i = blockIdx.x * blockDim.x + threadIdx.x;
    if (i < E) atomicAdd(&counts[dst[i]], 1);
}

// single-kernel exclusive scan (decoupled lookback) + rowptr/cur/dinv production.
__global__ __launch_bounds__(1024) void scan_lookback(const int* __restrict__ counts,
                                                      int* __restrict__ rowptr,
                                                      int* __restrict__ cur,
                                                      float* __restrict__ dinv,
                                                      unsigned long long* __restrict__ state,
                                                      int* __restrict__ ticket, int n, int E) {
    __shared__ int sh[1024];
    __shared__ int sbid, sexcl;
    int t = threadIdx.x;
    if (t == 0) sbid = atomicAdd(ticket, 1);
    __syncthreads();
    int bid = sbid;
    int g = bid * 1024 + t;
    int v = (g < n) ? counts[g] : 0;
    sh[t] = v;
    __syncthreads();
    for (int off = 1; off < 1024; off <<= 1) {
        int add = (t >= off) ? sh[t - off] : 0;
        __syncthreads();
        sh[t] += add;
        __syncthreads();
    }
    int total = sh[1023];
    if (t == 0) {
        if (bid == 0) {
            atomicExch(&state[0], (2ULL << 32) | (unsigned)total);
            sexcl = 0;
        } else {
            atomicExch(&state[bid], (1ULL << 32) | (unsigned)total);
            int excl = 0;
            int j = bid - 1;
            while (true) {
                unsigned long long s;
                do { s = atomicAdd(&state[j], 0ULL); } while ((s >> 32) == 0);
                excl += (int)(s & 0xffffffffULL);
                if ((s >> 32) == 2ULL) break;
                j--;
            }
            atomicExch(&state[bid], (2ULL << 32) | (unsigned)(excl + total));
            sexcl = excl;
        }
    }
    __syncthreads();
    int excl = sexcl;
    if (g < n) {
        int r = excl + sh[t] - v;  // exclusive prefix
        rowptr[g] = r;
        cur[g] = r;
        dinv[g] = rsqrtf((float)counts[g] + 1.0f);
    }
    if (g == 0) rowptr[n] = E;
}

// writes interleaved (src, weight) per slot — one 8B store
__global__ void fill_kernel(const int* __restrict__ src, const int* __restrict__ dst, int E,
                            int* __restrict__ cur, const float* __restrict__ dinv,
                            int2* __restrict__ edge) {
    int e = blockIdx.x * blockDim.x + threadIdx.x;
    if (e < E) {
        int d = dst[e];
        int s = src[e];
        int p = atomicAdd(&cur[d], 1);
        edge[p] = make_int2(s, __float_as_int(dinv[s] * dinv[d]));
    }
}

// ========= shared device helper: finalize math for one channel (see R1 derivation) ======
// m = sum/n, v = sumsq/n - m^2; t = bs*rsqrt(v*bs^2+eps), bs = rsqrt(v+eps)*g
__device__ inline void finalize_ch(float sum, float sumsq, float g, int n,
                                   float& m, float& t, float& vt2) {
    m = sum / n;
    float v = sumsq / n - m * m;
    v = v < 0.f ? 0.f : v;
    float bs = rsqrtf(v + EPS) * g;
    float vz = v * bs * bs;
    t = bs * rsqrtf(vz + EPS);
    vt2 = v * t * t;
}

// ================= MFMA GEMM: out[n,128] = norm(hb[n,K]) @ W, bf16 in/out =================
// NORM: computes per-channel (S,T) from raw sums+params in-block (uniform work).
// STATS: fused per-channel sum/sumsq of output via LDS + atomics.
template <int K, bool NORM, bool STATS>
__global__ __launch_bounds__(256) void gemm_mfma(const unsigned short* __restrict__ hb,
                                                 const unsigned short* __restrict__ Wt,
                                                 const float* __restrict__ sums_in,
                                                 const float* __restrict__ gw,
                                                 const float* __restrict__ lw,
                                                 const float* __restrict__ lb,
                                                 unsigned short* __restrict__ outb,
                                                 float* __restrict__ sums_out, int n) {
    __shared__ float sh_ss[NORM ? 256 : 1];
    __shared__ float sh_v[NORM ? 128 : 1];
    if (NORM) {
        int t = threadIdx.x;
        float m, tt, vt2;
        if (t < 128) {
            finalize_ch(sums_in[t], sums_in[128 + t], gw[t], n, m, tt, vt2);
            sh_v[t] = vt2;
        }
        __syncthreads();
        if (t == 0) {
            float gv = 0.f;
            for (int i = 0; i < 128; i++) gv += sh_v[i];
            sh_v[0] = gv / 128.f;
        }
        __syncthreads();
        if (t < 128) {
            float S = tt * rsqrtf(sh_v[0] + EPS) * lw[t];
            sh_ss[t] = S;
            sh_ss[128 + t] = lb[t] - m * S;
        }
        __syncthreads();
    }

    int wid = (blockIdx.x * 256 + threadIdx.x) >> 6;
    int wv = (threadIdx.x >> 6);
    int lane = threadIdx.x & 63;
    int m = lane & 15;
    int qd = lane >> 4;
    int r0 = wid * 32;
    if (!STATS && r0 >= n) return;

    f32x4 acc[2][8];
#pragma unroll
    for (int rt = 0; rt < 2; rt++)
#pragma unroll
        for (int ct = 0; ct < 8; ct++) acc[rt][ct] = (f32x4){0.f, 0.f, 0.f, 0.f};

    if (r0 < n) {
#pragma unroll
        for (int q = 0; q < K / 32; q++) {
            int k0 = q * 32 + qd * 8;
            bf16x8 a[2];
#pragma unroll
            for (int rt = 0; rt < 2; rt++) {
                int r = r0 + rt * 16 + m;
                bf16x8 av = (bf16x8){0, 0, 0, 0, 0, 0, 0, 0};
                if (r < n) av = *(const bf16x8*)(hb + (size_t)r * K + k0);
                if (NORM) {
#pragma unroll
                    for (int j = 0; j < 8; j++) {
                        float f = bf2f((unsigned short)av[j]);
                        f = fmaxf(fmaf(f, sh_ss[k0 + j], sh_ss[K + k0 + j]), 0.f);
                        av[j] = f2bf(f);
                    }
                }
                a[rt] = av;
            }
#pragma unroll
            for (int ct = 0; ct < 8; ct++) {
                bf16x8 b = *(const bf16x8*)(Wt + (size_t)(ct * 16 + m) * K + k0);
                acc[0][ct] = __builtin_amdgcn_mfma_f32_16x16x32_bf16(a[0], b, acc[0][ct], 0, 0, 0);
                acc[1][ct] = __builtin_amdgcn_mfma_f32_16x16x32_bf16(a[1], b, acc[1][ct], 0, 0, 0);
            }
        }
#pragma unroll
        for (int rt = 0; rt < 2; rt++)
#pragma unroll
            for (int i = 0; i < 4; i++) {
                int r = r0 + rt * 16 + qd * 4 + i;
                if (r < n) {
#pragma unroll
                    for (int ct = 0; ct < 8; ct++)
                        outb[(size_t)r * 128 + ct * 16 + m] = (unsigned short)f2bf(acc[rt][ct][i]);
                }
            }
    }

    if (STATS) {
        __shared__ float ls[4][128], lq[4][128];
#pragma unroll
        for (int ct = 0; ct < 8; ct++) {
            float s = 0.f, q = 0.f;
#pragma unroll
            for (int rt = 0; rt < 2; rt++)
#pragma unroll
                for (int i = 0; i < 4; i++) {
                    float v = acc[rt][ct][i];
                    s += v;
                    q += v * v;
                }
            s += __shfl_xor(s, 16, 64);
            s += __shfl_xor(s, 32, 64);
            q += __shfl_xor(q, 16, 64);
            q += __shfl_xor(q, 32, 64);
            if (qd == 0) {
                ls[wv][ct * 16 + m] = s;
                lq[wv][ct * 16 + m] = q;
            }
        }
        __syncthreads();
        int t = threadIdx.x;
        if (t < 128) {
            atomicAdd(&sums_out[t], ls[0][t] + ls[1][t] + ls[2][t] + ls[3][t]);
        } else {
            int c = t - 128;
            atomicAdd(&sums_out[128 + c], lq[0][c] + lq[1][c] + lq[2][c] + lq[3][c]);
        }
    }
}

// GEMV, bf16 input, in-block finalize of layer-2 norm: out[n] = relu(hb*S+T) @ W[128]
__global__ __launch_bounds__(256) void gemv_norm_bf(const unsigned short* __restrict__ hb,
                                                    const float* __restrict__ W,
                                                    const float* __restrict__ sums_in,
                                                    const float* __restrict__ gw,
                                                    const float* __restrict__ lw,
                                                    const float* __restrict__ lb,
                                                    float* __restrict__ out, int n) {
    __shared__ float sh_ss[256];
    __shared__ float sh_v[128];
    {
        int t = threadIdx.x;
        float m, tt, vt2;
        if (t < 128) {
            finalize_ch(sums_in[t], sums_in[128 + t], gw[t], n, m, tt, vt2);
            sh_v[t] = vt2;
        }
        __syncthreads();
        if (t == 0) {
            float gv = 0.f;
            for (int i = 0; i < 128; i++) gv += sh_v[i];
            sh_v[0] = gv / 128.f;
        }
        __syncthreads();
        if (t < 128) {
            float S = tt * rsqrtf(sh_v[0] + EPS) * lw[t];
            sh_ss[t] = S;
            sh_ss[128 + t] = lb[t] - m * S;
        }
        __syncthreads();
    }
    int gid = blockIdx.x * blockDim.x + threadIdx.x;
    int wid = gid >> 6, lane = gid & 63;
    int nw = (gridDim.x * blockDim.x) >> 6;
    int c = lane * 2;
    float w0 = W[c], w1 = W[c + 1];
    float s0 = sh_ss[c], s1 = sh_ss[c + 1];
    float t0 = sh_ss[128 + c], t1 = sh_ss[128 + c + 1];
    for (int r = wid; r < n; r += nw) {
        ushort2 u = ((const ushort2*)(hb + (size_t)r * 128))[lane];
        float a = fmaxf(fmaf(bf2f(u.x), s0, t0), 0.f);
        float b = fmaxf(fmaf(bf2f(u.y), s1, t1), 0.f);
        float v = fmaf(a, w0, b * w1);
#pragma unroll
        for (int off = 32; off > 0; off >>= 1) v += __shfl_down(v, off, 64);
        if (lane == 0) out[r] = v;
    }
}

// ================= agg128: 16 nodes/block, 16 lanes/node, u16x8, no barrier =============
__global__ __launch_bounds__(256) void agg128_bf(const unsigned short* __restrict__ tmp,
                                                 const int* __restrict__ rowptr,
                                                 const int2* __restrict__ edge,
                                                 const float* __restrict__ dinv,
                                                 unsigned short* __restrict__ agg, int n) {
    int node = (blockIdx.x << 4) + (threadIdx.x >> 4);
    if (node >= n) return;
    int co = (threadIdx.x & 15) << 3;  // 8-channel offset
    float di = dinv[node];
    float d2 = di * di;
    u16x8 t = *(const u16x8*)(tmp + ((size_t)node << 7) + co);
    float acc[8];
#pragma unroll
    for (int k = 0; k < 8; k++) acc[k] = bf2f(t[k]) * d2;
    int j = rowptr[node], je = rowptr[node + 1];
    for (; j + 8 <= je; j += 8) {
        int2 e[8];
        u16x8 v[8];
#pragma unroll
        for (int k = 0; k < 8; k++) e[k] = edge[j + k];
#pragma unroll
        for (int k = 0; k < 8; k++) v[k] = *(const u16x8*)(tmp + ((size_t)e[k].x << 7) + co);
#pragma unroll
        for (int k = 0; k < 8; k++) {
            float w = __int_as_float(e[k].y);
#pragma unroll
            for (int c = 0; c < 8; c++) acc[c] = fmaf(bf2f(v[k][c]), w, acc[c]);
        }
    }
    if (j + 4 <= je) {
        int2 e[4];
        u16x8 v[4];
#pragma unroll
        for (int k = 0; k < 4; k++) e[k] = edge[j + k];
#pragma unroll
        for (int k = 0; k < 4; k++) v[k] = *(const u16x8*)(tmp + ((size_t)e[k].x << 7) + co);
#pragma unroll
        for (int k = 0; k < 4; k++) {
            float w = __int_as_float(e[k].y);
#pragma unroll
            for (int c = 0; c < 8; c++) acc[c] = fmaf(bf2f(v[k][c]), w, acc[c]);
        }
        j += 4;
    }
    for (; j < je; j++) {
        int2 e = edge[j];
        float w = __int_as_float(e.y);
        u16x8 v = *(const u16x8*)(tmp + ((size_t)e.x << 7) + co);
#pragma unroll
        for (int c = 0; c < 8; c++) acc[c] = fmaf(bf2f(v[c]), w, acc[c]);
    }
    u16x8 o;
#pragma unroll
    for (int k = 0; k < 8; k++) o[k] = (unsigned short)f2bf(acc[k]);
    *(u16x8*)(agg + ((size_t)node << 7) + co) = o;
}

// ================= stats over bf16 matrix (uniform work) =================
__global__ __launch_bounds__(256) void stats128_bf(const unsigned short* __restrict__ a,
                                                   float* __restrict__ sums, int n) {
    __shared__ float ls[16][128], lq[16][128];
    int t = threadIdx.x;
    int rg = t >> 4;
    int cg = t & 15;
    float s[8], q[8];
#pragma unroll
    for (int k = 0; k < 8; k++) { s[k] = 0.f; q[k] = 0.f; }
    for (int r = blockIdx.x * 16 + rg; r < n; r += gridDim.x * 16) {
        u16x8 v = *(const u16x8*)(a + (size_t)r * 128 + cg * 8);
#pragma unroll
        for (int k = 0; k < 8; k++) {
            float f = bf2f(v[k]);
            s[k] += f;
            q[k] = fmaf(f, f, q[k]);
        }
    }
#pragma unroll
    for (int k = 0; k < 8; k++) {
        ls[rg][cg * 8 + k] = s[k];
        lq[rg][cg * 8 + k] = q[k];
    }
    __syncthreads();
    if (t < 128) {
        float v = 0.f;
#pragma unroll
        for (int i = 0; i < 16; i++) v += ls[i][t];
        atomicAdd(&sums[t], v);
    } else {
        int c = t - 128;
        float v = 0.f;
#pragma unroll
        for (int i = 0; i < 16; i++) v += lq[i][c];
        atomicAdd(&sums[128 + c], v);
    }
}

// ================= agg32: gather fp32 x, 8 lanes/node, float4 loads ============
__global__ __launch_bounds__(256) void agg32_f(const float* __restrict__ x,
                                               const int* __restrict__ rowptr,
                                               const int2* __restrict__ edge,
                                               const float* __restrict__ dinv,
                                               unsigned short* __restrict__ xab, int n) {
    int g = threadIdx.x >> 3;
    int lane = threadIdx.x & 7;
    int node = blockIdx.x * 32 + g;
    if (node >= n) return;
    int co = lane << 2;
    float di = dinv[node];
    float d2 = di * di;
    float4 a = *(const float4*)(x + ((size_t)node << 5) + co);
    a.x *= d2; a.y *= d2; a.z *= d2; a.w *= d2;
    int j = rowptr[node], je = rowptr[node + 1];
    for (; j + 4 <= je; j += 4) {
        int2 e0 = edge[j], e1 = edge[j + 1], e2 = edge[j + 2], e3 = edge[j + 3];
        float4 v0 = *(const float4*)(x + ((size_t)e0.x << 5) + co);
        float4 v1 = *(const float4*)(x + ((size_t)e1.x << 5) + co);
        float4 v2 = *(const float4*)(x + ((size_t)e2.x << 5) + co);
        float4 v3 = *(const float4*)(x + ((size_t)e3.x << 5) + co);
        float w0 = __int_as_float(e0.y), w1 = __int_as_float(e1.y);
        float w2 = __int_as_float(e2.y), w3 = __int_as_float(e3.y);
        a.x = fmaf(v0.x, w0, a.x); a.y = fmaf(v0.y, w0, a.y);
        a.z = fmaf(v0.z, w0, a.z); a.w = fmaf(v0.w, w0, a.w);
        a.x = fmaf(v1.x, w1, a.x); a.y = fmaf(v1.y, w1, a.y);
        a.z = fmaf(v1.z, w1, a.z); a.w = fmaf(v1.w, w1, a.w);
        a.x = fmaf(v2.x, w2, a.x); a.y = fmaf(v2.y, w2, a.y);
        a.z = fmaf(v2.z, w2, a.z); a.w = fmaf(v2.w, w2, a.w);
        a.x = fmaf(v3.x, w3, a.x); a.y = fmaf(v3.y, w3, a.y);
        a.z = fmaf(v3.z, w3, a.z); a.w = fmaf(v3.w, w3, a.w);
    }
    for (; j < je; j++) {
        int2 e = edge[j];
        float w = __int_as_float(e.y);
        float4 v = *(const float4*)(x + ((size_t)e.x << 5) + co);
        a.x = fmaf(v.x, w, a.x); a.y = fmaf(v.y, w, a.y);
        a.z = fmaf(v.z, w, a.z); a.w = fmaf(v.w, w, a.w);
    }
    ushort4 o;
    o.x = (unsigned short)f2bf(a.x);
    o.y = (unsigned short)f2bf(a.y);
    o.z = (unsigned short)f2bf(a.z);
    o.w = (unsigned short)f2bf(a.w);
    ((ushort4*)(xab + ((size_t)node << 5)))[lane] = o;
}

// ================= agg1: 1 thread/node, per-wave NON-ATOMIC stats partials ==============
__global__ void agg1_stats(const float* __restrict__ tmp, const int* __restrict__ rowptr,
                           const int2* __restrict__ edge, const float* __restrict__ dinv,
                           float* __restrict__ out, float* __restrict__ part, int n) {
    int i = blockIdx.x * blockDim.x + threadIdx.x;
    float acc = 0.f;
    if (i < n) {
        float di = dinv[i];
        acc = tmp[i] * di * di;
        int j = rowptr[i], je = rowptr[i + 1];
        for (; j + 4 <= je; j += 4) {
            int2 e0 = edge[j], e1 = edge[j + 1], e2 = edge[j + 2], e3 = edge[j + 3];
            float v0 = tmp[e0.x], v1 = tmp[e1.x], v2 = tmp[e2.x], v3 = tmp[e3.x];
            acc = fmaf(v0, __int_as_float(e0.y), acc);
            acc = fmaf(v1, __int_as_float(e1.y), acc);
            acc = fmaf(v2, __int_as_float(e2.y), acc);
            acc = fmaf(v3, __int_as_float(e3.y), acc);
        }
        for (; j < je; j++) {
            int2 e = edge[j];
            acc = fmaf(tmp[e.x], __int_as_float(e.y), acc);
        }
        out[i] = acc;
    }
    float s = acc, q = acc * acc;
#pragma unroll
    for (int off = 32; off > 0; off >>= 1) {
        s += __shfl_down(s, off, 64);
        q += __shfl_down(q, off, 64);
    }
    if ((threadIdx.x & 63) == 0) {
        int wgid = (blockIdx.x * blockDim.x + threadIdx.x) >> 6;
        part[2 * wgid] = s;
        part[2 * wgid + 1] = q;
    }
}

// apply with in-block partial reduction + inline C=1 finalize
__global__ __launch_bounds__(256) void apply1_kernel(const float* __restrict__ part, int nw,
                                                     const float* __restrict__ g,
                                                     const float* __restrict__ lw,
                                                     const float* __restrict__ lb,
                                                     const float* __restrict__ a,
                                                     float* __restrict__ out, int n) {
    __shared__ float ls[256], lq[256];
    int t = threadIdx.x;
    float s = 0.f, q = 0.f;
    for (int i = t; i < nw; i += 256) {
        s += part[2 * i];
        q += part[2 * i + 1];
    }
    ls[t] = s;
    lq[t] = q;
    __syncthreads();
    for (int off = 128; off > 0; off >>= 1) {
        if (t < off) {
            ls[t] += ls[t + off];
            lq[t] += lq[t + off];
        }
        __syncthreads();
    }
    float m = ls[0] / n;
    float v = lq[0] / n - m * m;
    v = v < 0.f ? 0.f : v;
    float bs = rsqrtf(v + EPS) * g[0];
    float vz = v * bs * bs;
    float tt = bs * rsqrtf(vz + EPS);
    float GV = v * tt * tt;
    float S = tt * rsqrtf(GV + EPS) * lw[0];
    float T = lb[0] - m * S;
    int i = blockIdx.x * blockDim.x + t;
    if (i < n) out[i] = fmaf(a[i], S, T);
}

extern "C" void kernel_launch(void* const* d_in, const int* in_sizes, int n_in,
                              void* d_out, int out_size, void* d_ws, size_t ws_size,
                              hipStream_t stream) {
    const float* x = (const float*)d_in[0];
    const int* ei = (const int*)d_in[1];
    int n = in_sizes[0] / 32;
    int E = in_sizes[1] / 2;
    const int* src = ei;
    const int* dstp = ei + E;
    const float* W1 = (const float*)d_in[2];
    const float* g1 = (const float*)d_in[4];
    const float* lw1 = (const float*)d_in[6];
    const float* lb1 = (const float*)d_in[7];
    const float* W2 = (const float*)d_in[8];
    const float* g2 = (const float*)d_in[10];
    const float* lw2 = (const float*)d_in[12];
    const float* lb2 = (const float*)d_in[13];
    const float* W3 = (const float*)d_in[14];
    const float* g3 = (const float*)d_in[16];
    const float* lw3 = (const float*)d_in[18];
    const float* lb3 = (const float*)d_in[19];
    float* out = (float*)d_out;

    // workspace layout (16B-aligned chunks)
    char* p = (char*)d_ws;
    int* counts = (int*)p;             p += (size_t)n * 4;
    int* cur = (int*)p;                p += (size_t)n * 4;
    int* rowptr = (int*)p;             p += (size_t)(n + 4) * 4;
    unsigned long long* state = (unsigned long long*)p;  p += 128 * 8;
    int* ticket = (int*)p;             p += 4 * 4;
    int2* edge = (int2*)p;             p += (size_t)E * 8;
    float* dinv = (float*)p;           p += (size_t)n * 4;
    unsigned short* Wt1 = (unsigned short*)p;  p += 128 * 32 * 2;
    unsigned short* Wt2 = (unsigned short*)p;  p += 128 * 128 * 2;
    unsigned short* xa = (unsigned short*)p;   p += (size_t)n * 32 * 2;
    unsigned short* h1 = (unsigned short*)p;   p += (size_t)n * 128 * 2;
    unsigned short* t2 = (unsigned short*)p;   p += (size_t)n * 128 * 2;
    unsigned short* a2 = (unsigned short*)p;   p += (size_t)n * 128 * 2;
    float* t3 = (float*)p;             p += (size_t)n * 4;
    float* a3 = (float*)p;             p += (size_t)n * 4;
    float* sums1 = (float*)p;          p += 256 * 4;
    float* sums2 = (float*)p;          p += 256 * 4;
    float* part3 = (float*)p;          p += ((size_t)(n + 255) / 256) * 4 * 2 * 4;

    int B = (n + 1023) / 1024;  // scan blocks (<=128 for n<=131072)

    // ---- prep + CSR build ----
    prep_kernel<<<(n + 255) / 256, 256, 0, stream>>>(W1, W2, Wt1, Wt2, counts, sums1,
                                                     state, ticket, n);
    hist_kernel<<<(E + 255) / 256, 256, 0, stream>>>(dstp, E, counts);
    scan_lookback<<<B, 1024, 0, stream>>>(counts, rowptr, cur, dinv, state, ticket, n, E);
    fill_kernel<<<(E + 255) / 256, 256, 0, stream>>>(src, dstp, E, cur, dinv, edge);

    int mblk = ((n + 31) / 32 + 3) / 4;

    // ---- layer 1: agg(x) in 32-dim, MFMA GEMM 32->128 with fused stats ----
    agg32_f<<<(n + 31) / 32, 256, 0, stream>>>(x, rowptr, edge, dinv, xa, n);
    gemm_mfma<32, false, true><<<mblk, 256, 0, stream>>>(xa, Wt1, nullptr, nullptr, nullptr,
                                                         nullptr, h1, sums1, n);

    // ---- layer 2: MFMA GEMM 128->128 (in-block finalize of norm1), agg, stats ----
    gemm_mfma<128, true, false><<<mblk, 256, 0, stream>>>(h1, Wt2, sums1, g1, lw1, lb1,
                                                          t2, nullptr, n);
    agg128_bf<<<(n + 15) / 16, 256, 0, stream>>>(t2, rowptr, edge, dinv, a2, n);
    stats128_bf<<<512, 256, 0, stream>>>(a2, sums2, n);

    // ---- layer 3: gemv (in-block finalize of norm2), agg + partials, apply ----
    int ablk1 = (n + 255) / 256;
    gemv_norm_bf<<<1024, 256, 0, stream>>>(a2, W3, sums2, g2, lw2, lb2, t3, n);
    agg1_stats<<<ablk1, 256, 0, stream>>>(t3, rowptr, edge, dinv, a3, part3, n);
    apply1_kernel<<<ablk1, 256, 0, stream>>>(part3, ablk1 * 4, g3, lw3, lb3, a3, out, n);
}